// Round 3
// 209.541 us; speedup vs baseline: 1.0595x; 1.0595x over previous
//
#include <hip/hip_runtime.h>
#include <hip/hip_fp16.h>

// Precoding GNN: 5 layers of z = Ws*x + Wm*(sum_k x) + Wk*(sum_m x), ReLU(1-4),
// then Frobenius power normalization per batch item.
// M=64 antennas, K=32 users, D=32 hidden, BS=1024. One 1024-thread block/item.
//
// R13 (from R12 @146us/dispatch, VALUBusy 61%, MfmaUtil 3.8% -> VALU-bound):
//  * X storage: two 16-feat planes, node-contiguous 32B rows:
//      dword addr = plane*16384 + node*8 + halfsel*4  (128 KiB total, was 144)
//    -> B-frag = single conflict-free ds_read_b128; act store = 2x ds_write_b64
//      (stride-18 layout forced 2x b64 reads: odd rows were not 16B aligned).
//  * phase_msg: all 1024 threads, 16 b128-read iters each (was 64/32/idle mix):
//      msg_k split 4-way over m-quarters (DPP quad_perm combine, VALU pipe),
//      msg_m split 2-way over k-halves; accumulate with v_pk_add_f16
//      (2 interleaved chains to bound fp16 error); XOR-rotation on msg_m's k
//      walk keeps the b128 reads bank-even.
//  * LAYER_SCALE (2^-7, exact in fp16) folded into weight fragments ->
//      epilogue is cvt_pkrtz + v_pk_max_f16 only (was fmax+mul+pack per elem).
//  * MFMA C-init: v_pk_add_f16(Am,Bk) + 4 cvt (was 16 cvt + 8 f32 add);
//      AB buffer stride 20 dwords with quad-interleaved h-halves -> Am/Bk are
//      one b128 each (Am wave-uniform broadcast).
//  * phase_small flipped like main: D = W x msg^T, b64 packed stores.
// R14: __hmax2 broken in ROCm 7.2 headers -> inline-asm v_pk_max_f16 %0,%1,0.
// R15: __builtin_amdgcn_cvt_pkrtz returns __fp16x2, not _Float16x2 ->
//      capture with auto + bit_cast to unsigned (no codegen change).
// Numerics: msg sums now fp16 chains (depth ~11, post-ReLU positive values);
// expected absmax ~5e-4 (was 2.44e-4). Scale folding is exact (pow2).

namespace {

constexpr int NTHREADS = 1024;
constexpr float INPUT_SCALE = 0.0625f;      // 2^-4 exact
constexpr float LAYER_SCALE = 0.0078125f;   // 2^-7 exact, folded into W frags
constexpr int XPLANE = 16384;               // dwords per feature plane

typedef _Float16 half8 __attribute__((ext_vector_type(8)));
typedef _Float16 half2v __attribute__((ext_vector_type(2)));
typedef float    f32x4 __attribute__((ext_vector_type(4)));
typedef unsigned uint4v __attribute__((ext_vector_type(4)));

#define RPT32(X) X(0)X(1)X(2)X(3)X(4)X(5)X(6)X(7)X(8)X(9)X(10)X(11)X(12)X(13)X(14)X(15) \
                 X(16)X(17)X(18)X(19)X(20)X(21)X(22)X(23)X(24)X(25)X(26)X(27)X(28)X(29)X(30)X(31)
#define RPT16P(X) X(0,0,1)X(1,2,3)X(2,4,5)X(3,6,7)X(4,8,9)X(5,10,11)X(6,12,13)X(7,14,15) \
                  X(8,16,17)X(9,18,19)X(10,20,21)X(11,22,23)X(12,24,25)X(13,26,27)X(14,28,29)X(15,30,31)

// AB buffer: 96 rows x 20 dwords (40 halves). Row r, h in [0,32):
// half offset = r*40 + ((h>>2)&3)*8 + ((h>>4)&1)*4 + (h&3)
// -> quad q's uint4 (dwords r*20+q*4..+3) = h {4q..4q+3, 16+4q..16+4q+3}.
#define AB_OFF(h) ((((h) >> 2) & 3) * 8 + (((h) >> 4) & 1) * 4 + ((h) & 3))

__device__ __forceinline__ float2 upk(unsigned w) {
    __half2 h;
    *reinterpret_cast<unsigned*>(&h) = w;
    return __half22float2(h);
}
__device__ __forceinline__ unsigned pkz(float a, float b) {   // v_cvt_pkrtz_f16_f32
    auto h = __builtin_amdgcn_cvt_pkrtz(a, b);   // __fp16 ext_vector(2)
    return __builtin_bit_cast(unsigned, h);
}
__device__ __forceinline__ unsigned hadd2u(unsigned a, unsigned b) {  // v_pk_add_f16
    half2v x = __builtin_bit_cast(half2v, a);
    half2v y = __builtin_bit_cast(half2v, b);
    return __builtin_bit_cast(unsigned, x + y);
}
__device__ __forceinline__ unsigned hmax0u(unsigned a) {      // v_pk_max_f16 with 0
    unsigned r;
    asm("v_pk_max_f16 %0, %1, 0" : "=v"(r) : "v"(a));
    return r;
}
// Cross-lane packed-fp16 add via DPP quad_perm (VALU pipe, no LDS traffic).
// CTRL 0xB1 = [1,0,3,2] (xor 1), 0x4E = [2,3,0,1] (xor 2).
template <int CTRL>
__device__ __forceinline__ uint4v dpp_hadd(uint4v s) {
    uint4v r;
    r.x = hadd2u(s.x, (unsigned)__builtin_amdgcn_mov_dpp((int)s.x, CTRL, 0xF, 0xF, true));
    r.y = hadd2u(s.y, (unsigned)__builtin_amdgcn_mov_dpp((int)s.y, CTRL, 0xF, 0xF, true));
    r.z = hadd2u(s.z, (unsigned)__builtin_amdgcn_mov_dpp((int)s.z, CTRL, 0xF, 0xF, true));
    r.w = hadd2u(s.w, (unsigned)__builtin_amdgcn_mov_dpp((int)s.w, CTRL, 0xF, 0xF, true));
    return r;
}

// Frag from weight W (d_out x 32 fp32, row-major): lane gets W[h][quad*8+j]*scale.
// scale = LAYER_SCALE is a power of 2 -> exact in fp16 (pure exponent shift).
__device__ __forceinline__ half8 load_wfrag(const float* __restrict__ W, int h, int quad,
                                            float scale) {
    const float4* wr = reinterpret_cast<const float4*>(W + h * 32 + quad * 8);
    const float4 w0 = wr[0];
    const float4 w1 = wr[1];
    half8 b;
    b[0] = (_Float16)(w0.x * scale); b[1] = (_Float16)(w0.y * scale);
    b[2] = (_Float16)(w0.z * scale); b[3] = (_Float16)(w0.w * scale);
    b[4] = (_Float16)(w1.x * scale); b[5] = (_Float16)(w1.y * scale);
    b[6] = (_Float16)(w1.z * scale); b[7] = (_Float16)(w1.w * scale);
    return b;
}

// ---- phase A: msg_m (MSG rows 0-63) and msg_k (rows 64-95), fp16x2 packed,
//      MSG row stride 20 dwords. All 1024 threads, 16 b128 reads each.
__device__ __forceinline__ void phase_msg(const unsigned* __restrict__ Xs,
                                          unsigned* __restrict__ MSG, int t) {
    if (t < 512) {
        // msg_k[k][feats fq*8..+7], partial over m-quarter mq, DPP-combined.
        const int k = t >> 4, fq = (t >> 2) & 3, mq = t & 3;
        const unsigned* p = Xs + (fq >> 1) * XPLANE + mq * 4096 + k * 8 + (fq & 1) * 4;
        half8 accA{}, accB{};
#pragma unroll
        for (int i = 0; i < 16; i += 2) {       // node = (mq*16+i)*32 + k
            accA += __builtin_bit_cast(half8, *(const uint4v*)(p + i * 256));
            accB += __builtin_bit_cast(half8, *(const uint4v*)(p + (i + 1) * 256));
        }
        uint4v s = __builtin_bit_cast(uint4v, accA + accB);
        s = dpp_hadd<0xB1>(s);
        s = dpp_hadd<0x4E>(s);
        if (mq == 0) *(uint4v*)(MSG + (64 + k) * 20 + fq * 4) = s;
    } else {
        // msg_m[m][feats fq*8..+7], partial over k-half kh, DPP-combined.
        const int u = t - 512;
        const int m = u >> 3, fq = (u >> 1) & 3, kh = u & 1;
        const unsigned* base = Xs + (fq >> 1) * XPLANE + m * 256 + kh * 128 + (fq & 1) * 4;
        const unsigned rot = (unsigned)((m & 15) * 8);  // k-walk XOR rotation: bank-even
        half8 accA{}, accB{};
#pragma unroll
        for (int i = 0; i < 16; i += 2) {       // node = m*32 + kh*16 + (i ^ (m&15))
            accA += __builtin_bit_cast(half8, *(const uint4v*)(base + (((unsigned)(i * 8)) ^ rot)));
            accB += __builtin_bit_cast(half8, *(const uint4v*)(base + (((unsigned)((i + 1) * 8)) ^ rot)));
        }
        uint4v s = __builtin_bit_cast(uint4v, accA + accB);
        s = dpp_hadd<0xB1>(s);
        if (kh == 0) *(uint4v*)(MSG + m * 20 + fq * 4) = s;
    }
}

// ---- phase B (flipped): D = W x msg^T. Lane (quad,col) holds D[h=ht*16+4q+r][row col]
//      -> one packed b64 store per wave into the quad-interleaved AB layout.
__device__ __forceinline__ void phase_small(const float* __restrict__ Wmg,
                                            const float* __restrict__ Wkg,
                                            const unsigned* __restrict__ MSG,
                                            unsigned* __restrict__ ABu, int t) {
    const int w = t >> 6, lane = t & 63;
    if (w < 12) {
        const int isb = (w >= 8);                 // B-part (Wk x msg_k)
        const int ww = isb ? (w - 8) : w;
        const int nt = ww >> 1, ht = ww & 1;      // node-tile, h-tile
        const int quad = lane >> 4, col = lane & 15;
        const int rowbase = (isb ? 64 : 0) + nt * 16;
        const uint4v mraw = *(const uint4v*)(MSG + (rowbase + col) * 20 + quad * 4);
        const half8 bfrag = __builtin_bit_cast(half8, mraw);   // B[d][n=row col]
        const half8 afrag = load_wfrag(isb ? Wkg : Wmg, ht * 16 + col, quad, LAYER_SCALE);
        f32x4 c = {0.f, 0.f, 0.f, 0.f};
        c = __builtin_amdgcn_mfma_f32_16x16x32_f16(afrag, bfrag, c, 0, 0, 0);
        uint2 st;
        st.x = pkz(c[0], c[1]);
        st.y = pkz(c[2], c[3]);
        *reinterpret_cast<uint2*>(ABu + (rowbase + col) * 20 + quad * 4 + ht * 2) = st;
    }
}

// ---- phase C: D = Ws_tile x X_group^T. C-init = pk_add(Am,Bk)+cvt; epilogue =
//      cvt_pkrtz + pk_max (scale pre-folded). X reads/writes node-contiguous.
__device__ __forceinline__ void phase_main(const float* __restrict__ Wsg,
                                           unsigned* __restrict__ Xs,
                                           const unsigned* __restrict__ ABu, int t) {
    const int w = t >> 6, lane = t & 63;
    const int quad = lane >> 4, col = lane & 15;
    const half8 a0 = load_wfrag(Wsg, col, quad, LAYER_SCALE);        // Ws rows h=col
    const half8 a1 = load_wfrag(Wsg, 16 + col, quad, LAYER_SCALE);   // h=col+16
    const uint4v* AB4 = reinterpret_cast<const uint4v*>(ABu);        // row stride 5 uint4
    const unsigned* xr = Xs + (quad >> 1) * XPLANE + col * 8 + (quad & 1) * 4;
    unsigned* xw = Xs + col * 8 + quad * 2;
#pragma unroll 2
    for (int i = 0; i < 8; ++i) {
        const int T = w + i * 16;          // node group: rows T*16..T*16+15
        const int node0 = T * 16;
        const int m = T >> 1;              // group shares antenna m (broadcast read)
        const int k0 = (T & 1) * 16;       // lane's user k = k0 + col
        const half8 b = __builtin_bit_cast(half8, *(const uint4v*)(xr + node0 * 8));
        const int krow = 64 + k0 + col;
        const uint4v Am = AB4[m * 5 + quad];       // h {4q..+3, 16+4q..+3} of A[m]
        const uint4v Bk = AB4[krow * 5 + quad];    // same h's of B[k]
        const float2 p00 = upk(hadd2u(Am.x, Bk.x));
        const float2 p01 = upk(hadd2u(Am.y, Bk.y));
        const float2 p10 = upk(hadd2u(Am.z, Bk.z));
        const float2 p11 = upk(hadd2u(Am.w, Bk.w));
        f32x4 c0 = {p00.x, p00.y, p01.x, p01.y};
        f32x4 c1 = {p10.x, p10.y, p11.x, p11.y};
        c0 = __builtin_amdgcn_mfma_f32_16x16x32_f16(a0, b, c0, 0, 0, 0);
        c1 = __builtin_amdgcn_mfma_f32_16x16x32_f16(a1, b, c1, 0, 0, 0);
        uint2 w0, w1;
        w0.x = hmax0u(pkz(c0[0], c0[1]));
        w0.y = hmax0u(pkz(c0[2], c0[3]));
        w1.x = hmax0u(pkz(c1[0], c1[1]));
        w1.y = hmax0u(pkz(c1[2], c1[3]));
        *reinterpret_cast<uint2*>(xw + node0 * 8) = w0;            // plane 0: h 4q..+3
        *reinterpret_cast<uint2*>(xw + node0 * 8 + XPLANE) = w1;   // plane 1: h 16+4q..+3
    }
}

__global__ void __launch_bounds__(NTHREADS) gnn_fused(
    const float* __restrict__ xg,
    const float* __restrict__ w1s, const float* __restrict__ w1m, const float* __restrict__ w1k,
    const float* __restrict__ w2s, const float* __restrict__ w2m, const float* __restrict__ w2k,
    const float* __restrict__ w3s, const float* __restrict__ w3m, const float* __restrict__ w3k,
    const float* __restrict__ w4s, const float* __restrict__ w4m, const float* __restrict__ w4k,
    const float* __restrict__ w5s, const float* __restrict__ w5m, const float* __restrict__ w5k,
    float* __restrict__ out)
{
    __shared__ __align__(16) unsigned Xs[2 * XPLANE];  // 2 feat-planes, 128 KiB
    __shared__ __align__(16) unsigned MSG[96 * 20];    // msg_m | msg_k, fp16x2
    __shared__ __align__(16) unsigned ABu[96 * 20];    // A | B, fp16, quad-interleaved
    __shared__ float red[17];

    const int t = threadIdx.x;
    const int b = blockIdx.x;
    const int k = t & 31;
    const int m1 = t >> 5;
    const int m2 = m1 + 32;
    const int lane = t & 63;
    const int wave = t >> 6;

    float2 a1 = *reinterpret_cast<const float2*>(xg + (size_t)b * 4096 + 2 * t);
    float2 a2 = *reinterpret_cast<const float2*>(xg + (size_t)b * 4096 + 2048 + 2 * t);
    a1.x *= INPUT_SCALE; a1.y *= INPUT_SCALE;
    a2.x *= INPUT_SCALE; a2.y *= INPUT_SCALE;

    _Float16* ABf = reinterpret_cast<_Float16*>(ABu);
    float* MSGf = reinterpret_cast<float*>(MSG);

    // ================= layer 1 (d_in=2, scalar path) =================
    if (t < 64) MSGf[t] = 0.f;
    __syncthreads();
    {
        float s0 = a1.x + a2.x, s1 = a1.y + a2.y;
        s0 += __shfl_xor(s0, 32);
        s1 += __shfl_xor(s1, 32);
        if (lane < 32) {
            atomicAdd(&MSGf[2 * k], s0);
            atomicAdd(&MSGf[2 * k + 1], s1);
        }
        float f0 = a1.x, f1 = a1.y, g0 = a2.x, g1 = a2.y;
#pragma unroll
        for (int mask = 1; mask <= 16; mask <<= 1) {
            f0 += __shfl_xor(f0, mask); f1 += __shfl_xor(f1, mask);
            g0 += __shfl_xor(g0, mask); g1 += __shfl_xor(g1, mask);
        }
        const float2 wm = *reinterpret_cast<const float2*>(w1m + 2 * k);
        ABf[m1 * 40 + AB_OFF(k)] = (_Float16)(wm.x * f0 + wm.y * f1);
        ABf[m2 * 40 + AB_OFF(k)] = (_Float16)(wm.x * g0 + wm.y * g1);
    }
    __syncthreads();
    {
        const int kk = t >> 5, hh = t & 31;
        const float2 wk2 = *reinterpret_cast<const float2*>(w1k + 2 * hh);
        ABf[(64 + kk) * 40 + AB_OFF(hh)] =
            (_Float16)(wk2.x * MSGf[2 * kk] + wk2.y * MSGf[2 * kk + 1]);
    }
    __syncthreads();
#pragma unroll 1
    for (int hf = 0; hf < 2; ++hf) {
        const int n = hf ? (t + 1024) : t;
        const int m = hf ? m2 : m1;
        const float xa = hf ? a2.x : a1.x;
        const float xb = hf ? a2.y : a1.y;
#define DECL_ACC(h) float acc##h = (float)ABf[m * 40 + AB_OFF(h)] \
                                 + (float)ABf[(64 + k) * 40 + AB_OFF(h)] \
                                 + w1s[h * 2] * xa + w1s[h * 2 + 1] * xb;
        RPT32(DECL_ACC)
#undef DECL_ACC
        unsigned tmp[16];
#define ST(p, h0, h1) tmp[p] = pkz(fmaxf(acc##h0, 0.f) * LAYER_SCALE, \
                                   fmaxf(acc##h1, 0.f) * LAYER_SCALE);
        RPT16P(ST)
#undef ST
        unsigned* xd = Xs + n * 8;
        uint4v v0, v1, v2, v3;
        v0.x = tmp[0];  v0.y = tmp[1];  v0.z = tmp[2];  v0.w = tmp[3];
        v1.x = tmp[4];  v1.y = tmp[5];  v1.z = tmp[6];  v1.w = tmp[7];
        v2.x = tmp[8];  v2.y = tmp[9];  v2.z = tmp[10]; v2.w = tmp[11];
        v3.x = tmp[12]; v3.y = tmp[13]; v3.z = tmp[14]; v3.w = tmp[15];
        *reinterpret_cast<uint4v*>(xd) = v0;
        *reinterpret_cast<uint4v*>(xd + 4) = v1;
        *reinterpret_cast<uint4v*>(xd + XPLANE) = v2;
        *reinterpret_cast<uint4v*>(xd + XPLANE + 4) = v3;
    }
    __syncthreads();

    // ================= layers 2-4 (MFMA path) =================
    phase_msg(Xs, MSG, t); __syncthreads();
    phase_small(w2m, w2k, MSG, ABu, t); __syncthreads();
    phase_main(w2s, Xs, ABu, t); __syncthreads();

    phase_msg(Xs, MSG, t); __syncthreads();
    phase_small(w3m, w3k, MSG, ABu, t); __syncthreads();
    phase_main(w3s, Xs, ABu, t); __syncthreads();

    phase_msg(Xs, MSG, t); __syncthreads();
    phase_small(w4m, w4k, MSG, ABu, t); __syncthreads();
    phase_main(w4s, Xs, ABu, t); __syncthreads();

    // ================= layer 5 (d_out=2, scalar) =================
    phase_msg(Xs, MSG, t); __syncthreads();
    if (t < 128) {                       // A5[m][h] = Wm5[h,:].msg_m[m]
        const int m = t & 63, h = t >> 6;
        float acc = 0.f;
#pragma unroll
        for (int p = 0; p < 16; ++p) {
            const float2 u = upk(MSG[m * 20 + p]);
            acc += w5m[h * 32 + 2 * p] * u.x + w5m[h * 32 + 2 * p + 1] * u.y;
        }
        ABf[m * 40 + h] = (_Float16)acc;             // AB_OFF(h)=h for h<4
    } else if (t < 192) {                // B5[k][h] = Wk5[h,:].msg_k[k]
        const int idx = t - 128;
        const int kk = idx & 31, h = idx >> 5;
        float acc = 0.f;
#pragma unroll
        for (int p = 0; p < 16; ++p) {
            const float2 u = upk(MSG[(64 + kk) * 20 + p]);
            acc += w5k[h * 32 + 2 * p] * u.x + w5k[h * 32 + 2 * p + 1] * u.y;
        }
        ABf[(64 + kk) * 40 + h] = (_Float16)acc;
    }
    __syncthreads();

    float za0 = (float)ABf[m1 * 40 + 0] + (float)ABf[(64 + k) * 40 + 0];
    float za1 = (float)ABf[m1 * 40 + 1] + (float)ABf[(64 + k) * 40 + 1];
    float zb0 = (float)ABf[m2 * 40 + 0] + (float)ABf[(64 + k) * 40 + 0];
    float zb1 = (float)ABf[m2 * 40 + 1] + (float)ABf[(64 + k) * 40 + 1];
    {
        const unsigned* xa0 = Xs + t * 8;
        const unsigned* xb0 = Xs + (t + 1024) * 8;
#pragma unroll
        for (int p = 0; p < 16; ++p) {
            const unsigned ua = (p < 8) ? xa0[p] : xa0[XPLANE + (p - 8)];
            const float2 u = upk(ua);
            za0 += w5s[2 * p] * u.x + w5s[2 * p + 1] * u.y;
            za1 += w5s[32 + 2 * p] * u.x + w5s[32 + 2 * p + 1] * u.y;
            const unsigned ub = (p < 8) ? xb0[p] : xb0[XPLANE + (p - 8)];
            const float2 v = upk(ub);
            zb0 += w5s[2 * p] * v.x + w5s[2 * p + 1] * v.y;
            zb1 += w5s[32 + 2 * p] * v.x + w5s[32 + 2 * p + 1] * v.y;
        }
    }

    // ---- pwr_norm (scale-invariant: all per-item multipliers cancel) ----
    float p2 = za0 * za0 + za1 * za1 + zb0 * zb0 + zb1 * zb1;
#pragma unroll
    for (int mask = 1; mask <= 32; mask <<= 1) p2 += __shfl_xor(p2, mask);
    if (lane == 0) red[wave] = p2;
    __syncthreads();
    if (t == 0) {
        float tot = 0.f;
#pragma unroll
        for (int i = 0; i < 16; ++i) tot += red[i];
        red[16] = rsqrtf(tot);
    }
    __syncthreads();
    const float alpha = red[16];

    float2 r1, r2;
    r1.x = alpha * za0; r1.y = alpha * za1;
    r2.x = alpha * zb0; r2.y = alpha * zb1;
    *reinterpret_cast<float2*>(out + (size_t)b * 4096 + 2 * t) = r1;
    *reinterpret_cast<float2*>(out + (size_t)b * 4096 + 2048 + 2 * t) = r2;
}

}  // namespace

extern "C" void kernel_launch(void* const* d_in, const int* in_sizes, int n_in,
                              void* d_out, int out_size, void* d_ws, size_t ws_size,
                              hipStream_t stream) {
    const float* xg  = (const float*)d_in[0];
    const float* w1s = (const float*)d_in[1];
    const float* w1m = (const float*)d_in[2];
    const float* w1k = (const float*)d_in[3];
    const float* w2s = (const float*)d_in[4];
    const float* w2m = (const float*)d_in[5];
    const float* w2k = (const float*)d_in[6];
    const float* w3s = (const float*)d_in[7];
    const float* w3m = (const float*)d_in[8];
    const float* w3k = (const float*)d_in[9];
    const float* w4s = (const float*)d_in[10];
    const float* w4m = (const float*)d_in[11];
    const float* w4k = (const float*)d_in[12];
    const float* w5s = (const float*)d_in[13];
    const float* w5m = (const float*)d_in[14];
    const float* w5k = (const float*)d_in[15];
    float* out = (float*)d_out;

    hipLaunchKernelGGL(gnn_fused, dim3(1024), dim3(NTHREADS), 0, stream,
                       xg, w1s, w1m, w1k, w2s, w2m, w2k, w3s, w3m, w3k,
                       w4s, w4m, w4k, w5s, w5m, w5k, out);
}

// Round 5
// 203.372 us; speedup vs baseline: 1.0916x; 1.0303x over previous
//
#include <hip/hip_runtime.h>
#include <hip/hip_fp16.h>

// Precoding GNN: 5 layers of z = Ws*x + Wm*(sum_k x) + Wk*(sum_m x), ReLU(1-4),
// then Frobenius power normalization per batch item.
// M=64 antennas, K=32 users, D=32 hidden, BS=1024. One 1024-thread block/item.
//
// R15 (130us/dispatch): VALU fixed (61->43%) but SQ_LDS_BANK_CONFLICT 4.6M->20M:
//   8-dword node rows repeat banks every 4 nodes; msg/main phases put 8 lanes
//   per 4-bank group. ~32us of the 130 is conflict serialization.
// R16: conflict-free layout, octet-exact (every consecutive-8-lane group of a
//   b128 access hits all 8 bank groups once):
//  * Xs rows: 16 dwords (64B) per node, chunk-swizzled:
//      dword = node*16 + ((chunk ^ ((node>>1)&3))<<2) + (dword&3)
//    Feature order permuted so chunk q = MFMA lane-q D-fragment
//    (halves [4q..4q+3, 16+4q..16+4q+3]); weight frags load the same
//    K-permutation from global (K-order arbitrary if A,B agree).
//    -> phase_main: B-read AND D-store are ONE b128 at the SAME address.
//  * phase_msg: k-mod-8 / m-rotation placed in lane-octet bits:
//      msg_k: (k,chunk,m-octant) 8-node sums, DPP row_ror:8 -> 4 quarter-sets
//      msg_m: (m,chunk,k3) sums over k=k3+8j (chunk' const, offsets static),
//             DPP xor1+xor2 -> 2 half-sets.  No cross-lane LDS ops.
//    Partial sets summed FREE by accumulating MFMAs in phase_small (MFMA ~4%).
//  * Layer-1 stores / layer-5 reads use the same swizzle+permutation.
// R17: resubmit of R16 (infra failure, no signal). Offline re-audit of layout
//   consistency, swizzle invariance, per-octet bank groups, DPP encodings: OK.
// Numerics: unchanged vs R15 (absmax 2.44e-4); LAYER_SCALE folding exact.

namespace {

constexpr int NTHREADS = 1024;
constexpr float INPUT_SCALE = 0.0625f;      // 2^-4 exact
constexpr float LAYER_SCALE = 0.0078125f;   // 2^-7 exact, folded into W frags

typedef _Float16 half8 __attribute__((ext_vector_type(8)));
typedef _Float16 half2v __attribute__((ext_vector_type(2)));
typedef float    f32x4 __attribute__((ext_vector_type(4)));
typedef unsigned uint4v __attribute__((ext_vector_type(4)));

#define RPT32(X) X(0)X(1)X(2)X(3)X(4)X(5)X(6)X(7)X(8)X(9)X(10)X(11)X(12)X(13)X(14)X(15) \
                 X(16)X(17)X(18)X(19)X(20)X(21)X(22)X(23)X(24)X(25)X(26)X(27)X(28)X(29)X(30)X(31)
#define RPT16P(X) X(0,0,1)X(1,2,3)X(2,4,5)X(3,6,7)X(4,8,9)X(5,10,11)X(6,12,13)X(7,14,15) \
                  X(8,16,17)X(9,18,19)X(10,20,21)X(11,22,23)X(12,24,25)X(13,26,27)X(14,28,29)X(15,30,31)

// AB buffer: 96 rows x 20 dwords (40 halves). Quad q's uint4 (dwords r*20+4q..+3)
// = halves [4q..4q+3, 16+4q..16+4q+3]  (same chunk content as Xs rows).
#define AB_OFF(h) ((((h) >> 2) & 3) * 8 + (((h) >> 4) & 1) * 4 + ((h) & 3))
// Feature-pair stored in slot s of a row: P(s) = 2*(s>>2) + 8*((s>>1)&1) + (s&1)
#define PSLOT(s) (2 * ((s) >> 2) + 8 * (((s) >> 1) & 1) + ((s) & 1))

__device__ __forceinline__ float2 upk(unsigned w) {
    __half2 h;
    *reinterpret_cast<unsigned*>(&h) = w;
    return __half22float2(h);
}
__device__ __forceinline__ unsigned pkz(float a, float b) {   // v_cvt_pkrtz_f16_f32
    auto h = __builtin_amdgcn_cvt_pkrtz(a, b);   // __fp16 ext_vector(2)
    return __builtin_bit_cast(unsigned, h);
}
__device__ __forceinline__ unsigned hadd2u(unsigned a, unsigned b) {  // v_pk_add_f16
    half2v x = __builtin_bit_cast(half2v, a);
    half2v y = __builtin_bit_cast(half2v, b);
    return __builtin_bit_cast(unsigned, x + y);
}
__device__ __forceinline__ unsigned hmax0u(unsigned a) {      // v_pk_max_f16 with 0
    unsigned r;
    asm("v_pk_max_f16 %0, %1, 0" : "=v"(r) : "v"(a));
    return r;
}
// Cross-lane packed-fp16 add via DPP (VALU pipe, no LDS traffic).
// 0xB1 quad_perm xor1, 0x4E quad_perm xor2, 0x128 row_ror:8 (lane^8 in 16-row).
template <int CTRL>
__device__ __forceinline__ uint4v dpp_hadd(uint4v s) {
    uint4v r;
    r.x = hadd2u(s.x, (unsigned)__builtin_amdgcn_mov_dpp((int)s.x, CTRL, 0xF, 0xF, true));
    r.y = hadd2u(s.y, (unsigned)__builtin_amdgcn_mov_dpp((int)s.y, CTRL, 0xF, 0xF, true));
    r.z = hadd2u(s.z, (unsigned)__builtin_amdgcn_mov_dpp((int)s.z, CTRL, 0xF, 0xF, true));
    r.w = hadd2u(s.w, (unsigned)__builtin_amdgcn_mov_dpp((int)s.w, CTRL, 0xF, 0xF, true));
    return r;
}

// Weight frag, PERMUTED K-order matching the chunk layout: lane (h, quad) gets
// halves [W[h][4q..4q+3], W[h][16+4q..16+4q+3]] * scale (pow2 -> exact fp16).
__device__ __forceinline__ half8 load_wfrag(const float* __restrict__ W, int h, int quad,
                                            float scale) {
    const float4 w0 = *reinterpret_cast<const float4*>(W + h * 32 + quad * 4);
    const float4 w1 = *reinterpret_cast<const float4*>(W + h * 32 + 16 + quad * 4);
    half8 b;
    b[0] = (_Float16)(w0.x * scale); b[1] = (_Float16)(w0.y * scale);
    b[2] = (_Float16)(w0.z * scale); b[3] = (_Float16)(w0.w * scale);
    b[4] = (_Float16)(w1.x * scale); b[5] = (_Float16)(w1.y * scale);
    b[6] = (_Float16)(w1.z * scale); b[7] = (_Float16)(w1.w * scale);
    return b;
}

// ---- phase A: messages. MSG rows (stride 20 dwords, slot order = chunk order):
//   msg_m set A/B (k mod 8 in {0-3}/{4-7}): rows 0-63 / 64-127
//   msg_k quarter qi (m in qi*16..+15):     rows 128+qi*32+k  (128-255)
__device__ __forceinline__ void phase_msg(const unsigned* __restrict__ Xs,
                                          unsigned* __restrict__ MSG, int t) {
    const int l = t & 63, w = t >> 6;
    {   // msg_k: thread (k, chunk, mo) sums nodes m = mo*8+j; octet spreads k3.
        const int k3 = l & 7;
        const int k = ((w & 3) << 3) | k3;
        const int chunk = w >> 2;
        const int mo = l >> 3;
        const int chunkp = chunk ^ ((k3 >> 1) & 3);
        const unsigned* p = Xs + mo * 4096 + k * 16 + chunkp * 4;
        half8 acc{};
#pragma unroll
        for (int j = 0; j < 8; ++j)
            acc += __builtin_bit_cast(half8, *(const uint4v*)(p + j * 512));
        uint4v s = __builtin_bit_cast(uint4v, acc);
        s = dpp_hadd<0x128>(s);                    // combine mo bit0 (lane^8)
        if ((l & 8) == 0) {
            const int qi = l >> 4;                 // m-quarter
            *(uint4v*)(MSG + (128 + qi * 32 + k) * 20 + chunk * 4) = s;
        }
    }
    {   // msg_m: thread (mlow,+32, chunk, k3) sums k = k3+8j; octet spreads k3;
        // chunk' constant (8j>>1 = 0 mod 4) -> all offsets compile-time.
        const int k3 = l & 7;
        const int chunk = (l >> 3) & 3;
        const int mlow = ((l >> 5) & 1) | ((w & 15) << 1);
        const int chunkp = chunk ^ ((k3 >> 1) & 3);
        const unsigned* p = Xs + mlow * 512 + k3 * 16 + chunkp * 4;
        half8 accA{}, accB{};
#pragma unroll
        for (int j = 0; j < 4; ++j) {
            accA += __builtin_bit_cast(half8, *(const uint4v*)(p + j * 128));
            accB += __builtin_bit_cast(half8, *(const uint4v*)(p + 16384 + j * 128));
        }
        uint4v sA = __builtin_bit_cast(uint4v, accA);
        uint4v sB = __builtin_bit_cast(uint4v, accB);
        sA = dpp_hadd<0xB1>(sA); sA = dpp_hadd<0x4E>(sA);
        sB = dpp_hadd<0xB1>(sB); sB = dpp_hadd<0x4E>(sB);
        if ((l & 3) == 0) {
            const int set = (l >> 2) & 1;          // k3 quad {0-3} vs {4-7}
            *(uint4v*)(MSG + (mlow + set * 64) * 20 + chunk * 4) = sA;
            *(uint4v*)(MSG + (mlow + 32 + set * 64) * 20 + chunk * 4) = sB;
        }
    }
}

// ---- phase B: D = W x msg^T with partial-set summation folded into the MFMA
//      accumulator (A-part: 2 half-sets; B-part: 4 quarter-sets).
__device__ __forceinline__ void phase_small(const float* __restrict__ Wmg,
                                            const float* __restrict__ Wkg,
                                            const unsigned* __restrict__ MSG,
                                            unsigned* __restrict__ ABu, int t) {
    const int w = t >> 6, lane = t & 63;
    if (w < 12) {
        const int isb = (w >= 8);                 // B-part (Wk x msg_k)
        const int ww = isb ? (w - 8) : w;
        const int nt = ww >> 1, ht = ww & 1;
        const int quad = lane >> 4, col = lane & 15;
        const half8 afrag = load_wfrag(isb ? Wkg : Wmg, ht * 16 + col, quad, LAYER_SCALE);
        f32x4 c = {0.f, 0.f, 0.f, 0.f};
        if (isb) {
            const int r0 = 128 + nt * 16 + col;
#pragma unroll
            for (int s = 0; s < 4; ++s) {
                const half8 bf = __builtin_bit_cast(half8,
                    *(const uint4v*)(MSG + (r0 + s * 32) * 20 + quad * 4));
                c = __builtin_amdgcn_mfma_f32_16x16x32_f16(afrag, bf, c, 0, 0, 0);
            }
        } else {
            const int r0 = nt * 16 + col;
#pragma unroll
            for (int s = 0; s < 2; ++s) {
                const half8 bf = __builtin_bit_cast(half8,
                    *(const uint4v*)(MSG + (r0 + s * 64) * 20 + quad * 4));
                c = __builtin_amdgcn_mfma_f32_16x16x32_f16(afrag, bf, c, 0, 0, 0);
            }
        }
        uint2 st;
        st.x = pkz(c[0], c[1]);
        st.y = pkz(c[2], c[3]);
        const int abrow = (isb ? 64 : 0) + nt * 16 + col;
        *reinterpret_cast<uint2*>(ABu + abrow * 20 + quad * 4 + ht * 2) = st;
    }
}

// ---- phase C: D = Ws_tile x X_group^T, in-place. Lane (q,c): chunk q of node
//      (node0+c) is read (B-frag) and written (D) as ONE b128 at one address.
__device__ __forceinline__ void phase_main(const float* __restrict__ Wsg,
                                           unsigned* __restrict__ Xs,
                                           const unsigned* __restrict__ ABu, int t) {
    const int w = t >> 6, lane = t & 63;
    const int quad = lane >> 4, col = lane & 15;
    const half8 a0 = load_wfrag(Wsg, col, quad, LAYER_SCALE);        // h = col
    const half8 a1 = load_wfrag(Wsg, 16 + col, quad, LAYER_SCALE);   // h = col+16
    const uint4v* AB4 = reinterpret_cast<const uint4v*>(ABu);        // stride 5 uint4
    unsigned* xp = Xs + col * 16 + ((quad ^ ((col >> 1) & 3)) << 2); // swizzled chunk
#pragma unroll 2
    for (int i = 0; i < 8; ++i) {
        const int T = w + i * 16;          // node group T*16..T*16+15
        const int m = T >> 1;
        const int k0 = (T & 1) << 4;
        unsigned* xc = xp + T * 256;
        const half8 b = __builtin_bit_cast(half8, *(const uint4v*)xc);
        const int krow = 64 + k0 + col;
        const uint4v Am = AB4[m * 5 + quad];       // broadcast (wave-uniform row)
        const uint4v Bk = AB4[krow * 5 + quad];
        const float2 p00 = upk(hadd2u(Am.x, Bk.x));
        const float2 p01 = upk(hadd2u(Am.y, Bk.y));
        const float2 p10 = upk(hadd2u(Am.z, Bk.z));
        const float2 p11 = upk(hadd2u(Am.w, Bk.w));
        f32x4 c0 = {p00.x, p00.y, p01.x, p01.y};
        f32x4 c1 = {p10.x, p10.y, p11.x, p11.y};
        c0 = __builtin_amdgcn_mfma_f32_16x16x32_f16(a0, b, c0, 0, 0, 0);
        c1 = __builtin_amdgcn_mfma_f32_16x16x32_f16(a1, b, c1, 0, 0, 0);
        uint4v st;
        st.x = hmax0u(pkz(c0[0], c0[1]));
        st.y = hmax0u(pkz(c0[2], c0[3]));
        st.z = hmax0u(pkz(c1[0], c1[1]));
        st.w = hmax0u(pkz(c1[2], c1[3]));
        *(uint4v*)xc = st;
    }
}

__global__ void __launch_bounds__(NTHREADS) gnn_fused(
    const float* __restrict__ xg,
    const float* __restrict__ w1s, const float* __restrict__ w1m, const float* __restrict__ w1k,
    const float* __restrict__ w2s, const float* __restrict__ w2m, const float* __restrict__ w2k,
    const float* __restrict__ w3s, const float* __restrict__ w3m, const float* __restrict__ w3k,
    const float* __restrict__ w4s, const float* __restrict__ w4m, const float* __restrict__ w4k,
    const float* __restrict__ w5s, const float* __restrict__ w5m, const float* __restrict__ w5k,
    float* __restrict__ out)
{
    __shared__ __align__(16) unsigned Xs[2048 * 16];   // 128 KiB, swizzled rows
    __shared__ __align__(16) unsigned MSG[256 * 20];   // msg partial sets, 20 KiB
    __shared__ __align__(16) unsigned ABu[96 * 20];    // A | B, fp16, 7.5 KiB
    __shared__ float red[17];

    const int t = threadIdx.x;
    const int b = blockIdx.x;
    const int k = t & 31;
    const int m1 = t >> 5;
    const int m2 = m1 + 32;
    const int lane = t & 63;
    const int wave = t >> 6;
    const int sw1 = (t >> 1) & 3;      // chunk swizzle for nodes t and t+1024

    float2 a1 = *reinterpret_cast<const float2*>(xg + (size_t)b * 4096 + 2 * t);
    float2 a2 = *reinterpret_cast<const float2*>(xg + (size_t)b * 4096 + 2048 + 2 * t);
    a1.x *= INPUT_SCALE; a1.y *= INPUT_SCALE;
    a2.x *= INPUT_SCALE; a2.y *= INPUT_SCALE;

    _Float16* ABf = reinterpret_cast<_Float16*>(ABu);
    float* MSGf = reinterpret_cast<float*>(MSG);

    // ================= layer 1 (d_in=2, scalar path) =================
    if (t < 64) MSGf[t] = 0.f;
    __syncthreads();
    {
        float s0 = a1.x + a2.x, s1 = a1.y + a2.y;
        s0 += __shfl_xor(s0, 32);
        s1 += __shfl_xor(s1, 32);
        if (lane < 32) {
            atomicAdd(&MSGf[2 * k], s0);
            atomicAdd(&MSGf[2 * k + 1], s1);
        }
        float f0 = a1.x, f1 = a1.y, g0 = a2.x, g1 = a2.y;
#pragma unroll
        for (int mask = 1; mask <= 16; mask <<= 1) {
            f0 += __shfl_xor(f0, mask); f1 += __shfl_xor(f1, mask);
            g0 += __shfl_xor(g0, mask); g1 += __shfl_xor(g1, mask);
        }
        const float2 wm = *reinterpret_cast<const float2*>(w1m + 2 * k);
        ABf[m1 * 40 + AB_OFF(k)] = (_Float16)(wm.x * f0 + wm.y * f1);
        ABf[m2 * 40 + AB_OFF(k)] = (_Float16)(wm.x * g0 + wm.y * g1);
    }
    __syncthreads();
    {
        const int kk = t >> 5, hh = t & 31;
        const float2 wk2 = *reinterpret_cast<const float2*>(w1k + 2 * hh);
        ABf[(64 + kk) * 40 + AB_OFF(hh)] =
            (_Float16)(wk2.x * MSGf[2 * kk] + wk2.y * MSGf[2 * kk + 1]);
    }
    __syncthreads();
#pragma unroll 1
    for (int hf = 0; hf < 2; ++hf) {
        const int n = hf ? (t + 1024) : t;
        const int m = hf ? m2 : m1;
        const float xa = hf ? a2.x : a1.x;
        const float xb = hf ? a2.y : a1.y;
#define DECL_ACC(h) float acc##h = (float)ABf[m * 40 + AB_OFF(h)] \
                                 + (float)ABf[(64 + k) * 40 + AB_OFF(h)] \
                                 + w1s[h * 2] * xa + w1s[h * 2 + 1] * xb;
        RPT32(DECL_ACC)
#undef DECL_ACC
        unsigned tmp[16];
#define ST(p, h0, h1) tmp[p] = pkz(fmaxf(acc##h0, 0.f) * LAYER_SCALE, \
                                   fmaxf(acc##h1, 0.f) * LAYER_SCALE);
        RPT16P(ST)
#undef ST
        unsigned* xd = Xs + n * 16;
        uint4v v0, v1, v2, v3;                       // chunk q = pairs {2q,2q+1,8+2q,8+2q+1}
        v0.x = tmp[0]; v0.y = tmp[1]; v0.z = tmp[8];  v0.w = tmp[9];
        v1.x = tmp[2]; v1.y = tmp[3]; v1.z = tmp[10]; v1.w = tmp[11];
        v2.x = tmp[4]; v2.y = tmp[5]; v2.z = tmp[12]; v2.w = tmp[13];
        v3.x = tmp[6]; v3.y = tmp[7]; v3.z = tmp[14]; v3.w = tmp[15];
        *(uint4v*)(xd + ((0 ^ sw1) << 2)) = v0;
        *(uint4v*)(xd + ((1 ^ sw1) << 2)) = v1;
        *(uint4v*)(xd + ((2 ^ sw1) << 2)) = v2;
        *(uint4v*)(xd + ((3 ^ sw1) << 2)) = v3;
    }
    __syncthreads();

    // ================= layers 2-4 (MFMA path) =================
    phase_msg(Xs, MSG, t); __syncthreads();
    phase_small(w2m, w2k, MSG, ABu, t); __syncthreads();
    phase_main(w2s, Xs, ABu, t); __syncthreads();

    phase_msg(Xs, MSG, t); __syncthreads();
    phase_small(w3m, w3k, MSG, ABu, t); __syncthreads();
    phase_main(w3s, Xs, ABu, t); __syncthreads();

    phase_msg(Xs, MSG, t); __syncthreads();
    phase_small(w4m, w4k, MSG, ABu, t); __syncthreads();
    phase_main(w4s, Xs, ABu, t); __syncthreads();

    // ================= layer 5 (d_out=2, scalar) =================
    phase_msg(Xs, MSG, t); __syncthreads();
    if (t < 128) {                       // A5[m][h] = Wm5[h,:].msg_m[m] (2 sets)
        const int m = t & 63, h = t >> 6;
        float acc = 0.f;
#pragma unroll
        for (int s = 0; s < 16; ++s) {
            const int pp = PSLOT(s);
            const float2 uA = upk(MSG[m * 20 + s]);
            const float2 uB = upk(MSG[(64 + m) * 20 + s]);
            acc += w5m[h * 32 + 2 * pp] * (uA.x + uB.x)
                 + w5m[h * 32 + 2 * pp + 1] * (uA.y + uB.y);
        }
        ABf[m * 40 + h] = (_Float16)acc;             // AB_OFF(h)=h for h<4
    } else if (t < 192) {                // B5[k][h] = Wk5[h,:].msg_k[k] (4 sets)
        const int idx = t - 128;
        const int kk = idx & 31, h = idx >> 5;
        float acc = 0.f;
#pragma unroll
        for (int s = 0; s < 16; ++s) {
            const int pp = PSLOT(s);
            float ux = 0.f, uy = 0.f;
#pragma unroll
            for (int qq = 0; qq < 4; ++qq) {
                const float2 u = upk(MSG[(128 + qq * 32 + kk) * 20 + s]);
                ux += u.x; uy += u.y;
            }
            acc += w5k[h * 32 + 2 * pp] * ux + w5k[h * 32 + 2 * pp + 1] * uy;
        }
        ABf[(64 + kk) * 40 + h] = (_Float16)acc;
    }
    __syncthreads();

    float za0 = (float)ABf[m1 * 40 + 0] + (float)ABf[(64 + k) * 40 + 0];
    float za1 = (float)ABf[m1 * 40 + 1] + (float)ABf[(64 + k) * 40 + 1];
    float zb0 = (float)ABf[m2 * 40 + 0] + (float)ABf[(64 + k) * 40 + 0];
    float zb1 = (float)ABf[m2 * 40 + 1] + (float)ABf[(64 + k) * 40 + 1];
    {
        const unsigned* xa0 = Xs + t * 16;
        const unsigned* xb0 = xa0 + 16384;           // node t+1024, same sw1
#pragma unroll
        for (int s = 0; s < 16; ++s) {
            const int idx = ((((s >> 2) ^ sw1) << 2)) | (s & 3);
            const int pp = PSLOT(s);
            const float2 u = upk(xa0[idx]);
            za0 += w5s[2 * pp] * u.x + w5s[2 * pp + 1] * u.y;
            za1 += w5s[32 + 2 * pp] * u.x + w5s[32 + 2 * pp + 1] * u.y;
            const float2 v = upk(xb0[idx]);
            zb0 += w5s[2 * pp] * v.x + w5s[2 * pp + 1] * v.y;
            zb1 += w5s[32 + 2 * pp] * v.x + w5s[32 + 2 * pp + 1] * v.y;
        }
    }

    // ---- pwr_norm (scale-invariant: all per-item multipliers cancel) ----
    float p2 = za0 * za0 + za1 * za1 + zb0 * zb0 + zb1 * zb1;
#pragma unroll
    for (int mask = 1; mask <= 32; mask <<= 1) p2 += __shfl_xor(p2, mask);
    if (lane == 0) red[wave] = p2;
    __syncthreads();
    if (t == 0) {
        float tot = 0.f;
#pragma unroll
        for (int i = 0; i < 16; ++i) tot += red[i];
        red[16] = rsqrtf(tot);
    }
    __syncthreads();
    const float alpha = red[16];

    float2 r1, r2;
    r1.x = alpha * za0; r1.y = alpha * za1;
    r2.x = alpha * zb0; r2.y = alpha * zb1;
    *reinterpret_cast<float2*>(out + (size_t)b * 4096 + 2 * t) = r1;
    *reinterpret_cast<float2*>(out + (size_t)b * 4096 + 2048 + 2 * t) = r2;
}

}  // namespace

extern "C" void kernel_launch(void* const* d_in, const int* in_sizes, int n_in,
                              void* d_out, int out_size, void* d_ws, size_t ws_size,
                              hipStream_t stream) {
    const float* xg  = (const float*)d_in[0];
    const float* w1s = (const float*)d_in[1];
    const float* w1m = (const float*)d_in[2];
    const float* w1k = (const float*)d_in[3];
    const float* w2s = (const float*)d_in[4];
    const float* w2m = (const float*)d_in[5];
    const float* w2k = (const float*)d_in[6];
    const float* w3s = (const float*)d_in[7];
    const float* w3m = (const float*)d_in[8];
    const float* w3k = (const float*)d_in[9];
    const float* w4s = (const float*)d_in[10];
    const float* w4m = (const float*)d_in[11];
    const float* w4k = (const float*)d_in[12];
    const float* w5s = (const float*)d_in[13];
    const float* w5m = (const float*)d_in[14];
    const float* w5k = (const float*)d_in[15];
    float* out = (float*)d_out;

    hipLaunchKernelGGL(gnn_fused, dim3(1024), dim3(NTHREADS), 0, stream,
                       xg, w1s, w1m, w1k, w2s, w2m, w2k, w3s, w3m, w3k,
                       w4s, w4m, w4k, w5s, w5m, w5k, out);
}

// Round 8
// 201.082 us; speedup vs baseline: 1.1040x; 1.0114x over previous
//
#include <hip/hip_runtime.h>
#include <hip/hip_fp16.h>

// Precoding GNN: 5 layers of z = Ws*x + Wm*(sum_k x) + Wk*(sum_m x), ReLU(1-4),
// then Frobenius power normalization per batch item.
// M=64 antennas, K=32 users, D=32 hidden, BS=1024. One 1024-thread block/item.
//
// R16/17 (122us): conflicts 20M->6.6M; latency/phase-bound at 1 block/CU.
// R18 (FAILED numerics 9.3e-3): single-set msg_m used dpp row_ror:4 to combine
//   k3-quads, but chunk lives in lane bits 3-4 and ror:4's direction decides
//   whether lane 0 combines with lane 4 (same chunk) or lane 12 (WRONG chunk).
//   ror:8 was only ever safe because (i+8)&15 == (i-8)&15 == i^8 (symmetric).
// R19: revert msg_m to the R17-proven TWO-set scheme (quad_perm xor1+xor2 only
//   -- XOR is direction-unambiguous); phase_small A-part = 2 accumulating
//   MFMAs. MSGM: 128 rows x 16 dwords, chunk^((row>>1)&3) XOR swizzle (same
//   family as MSGK; per-octet read = all 8 bank groups, write <=2-way).
//   LDS 131072+16384+8192+7680+68 = 163396 <= 163840. Kept from R18:
//  * msg_k from registers in phase_main (thread's 8 nodes share k): partial
//    written as ONE b128 to MSGK[8 sets]; phase_small sums sets via
//    accumulating MFMAs. Deletes 8 msg_k LDS reads/thread for layers 3-5.
//  * MSGK dense stride-16 + XOR swizzle (per-octet bank-exact all paths).
//  * L5: B5 spread over 256 threads (4-way set-split + shfl_xor), A5 2-set
//    rot-rotated reads; phase_main unroll 4.
// R20: byte-identical resubmit of R19 (second infra failure, no signal).
// Numerics: msg_m summation = exactly R17's tree; msg_k re-association only.

namespace {

constexpr int NTHREADS = 1024;
constexpr float INPUT_SCALE = 0.0625f;      // 2^-4 exact
constexpr float LAYER_SCALE = 0.0078125f;   // 2^-7 exact, folded into W frags

typedef _Float16 half8 __attribute__((ext_vector_type(8)));
typedef _Float16 half2v __attribute__((ext_vector_type(2)));
typedef float    f32x4 __attribute__((ext_vector_type(4)));
typedef unsigned uint4v __attribute__((ext_vector_type(4)));

#define RPT32(X) X(0)X(1)X(2)X(3)X(4)X(5)X(6)X(7)X(8)X(9)X(10)X(11)X(12)X(13)X(14)X(15) \
                 X(16)X(17)X(18)X(19)X(20)X(21)X(22)X(23)X(24)X(25)X(26)X(27)X(28)X(29)X(30)X(31)
#define RPT16P(X) X(0,0,1)X(1,2,3)X(2,4,5)X(3,6,7)X(4,8,9)X(5,10,11)X(6,12,13)X(7,14,15) \
                  X(8,16,17)X(9,18,19)X(10,20,21)X(11,22,23)X(12,24,25)X(13,26,27)X(14,28,29)X(15,30,31)

// AB buffer: 96 rows x 20 dwords. Quad q's uint4 = halves [4q..4q+3, 16+4q..+3].
#define AB_OFF(h) ((((h) >> 2) & 3) * 8 + (((h) >> 4) & 1) * 4 + ((h) & 3))
// Feature-pair stored in slot s of a row: P(s) = 2*(s>>2) + 8*((s>>1)&1) + (s&1)
#define PSLOT(s) (2 * ((s) >> 2) + 8 * (((s) >> 1) & 1) + ((s) & 1))

// MSGK: 8 partial sets, dense 16-dword rows, XOR-swizzled chunk position.
__device__ __forceinline__ int msgk_off(int set, int k, int chunk) {
    return set * 512 + k * 16 + ((chunk ^ ((k >> 1) & 3)) << 2);
}
// MSGM: 2 partial sets (k3 quads {0-3}/{4-7}) x 64 m, dense 16-dword rows.
__device__ __forceinline__ int msgm_off(int row, int chunk) {
    return row * 16 + ((chunk ^ ((row >> 1) & 3)) << 2);
}

__device__ __forceinline__ float2 upk(unsigned w) {
    __half2 h;
    *reinterpret_cast<unsigned*>(&h) = w;
    return __half22float2(h);
}
__device__ __forceinline__ unsigned pkz(float a, float b) {   // v_cvt_pkrtz_f16_f32
    auto h = __builtin_amdgcn_cvt_pkrtz(a, b);   // __fp16 ext_vector(2)
    return __builtin_bit_cast(unsigned, h);
}
__device__ __forceinline__ unsigned hadd2u(unsigned a, unsigned b) {  // v_pk_add_f16
    half2v x = __builtin_bit_cast(half2v, a);
    half2v y = __builtin_bit_cast(half2v, b);
    return __builtin_bit_cast(unsigned, x + y);
}
__device__ __forceinline__ unsigned hmax0u(unsigned a) {      // v_pk_max_f16 with 0
    unsigned r;
    asm("v_pk_max_f16 %0, %1, 0" : "=v"(r) : "v"(a));
    return r;
}
// Cross-lane packed-fp16 add via DPP (VALU pipe, no LDS traffic).
// ONLY XOR-symmetric controls: 0xB1 quad_perm xor1, 0x4E quad_perm xor2,
// 0x128 row_ror:8 ((i+8)&15 == i^8, direction-proof).
template <int CTRL>
__device__ __forceinline__ uint4v dpp_hadd(uint4v s) {
    uint4v r;
    r.x = hadd2u(s.x, (unsigned)__builtin_amdgcn_mov_dpp((int)s.x, CTRL, 0xF, 0xF, true));
    r.y = hadd2u(s.y, (unsigned)__builtin_amdgcn_mov_dpp((int)s.y, CTRL, 0xF, 0xF, true));
    r.z = hadd2u(s.z, (unsigned)__builtin_amdgcn_mov_dpp((int)s.z, CTRL, 0xF, 0xF, true));
    r.w = hadd2u(s.w, (unsigned)__builtin_amdgcn_mov_dpp((int)s.w, CTRL, 0xF, 0xF, true));
    return r;
}

// Weight frag, PERMUTED K-order matching the chunk layout: lane (h, quad) gets
// halves [W[h][4q..4q+3], W[h][16+4q..16+4q+3]] * scale (pow2 -> exact fp16).
__device__ __forceinline__ half8 load_wfrag(const float* __restrict__ W, int h, int quad,
                                            float scale) {
    const float4 w0 = *reinterpret_cast<const float4*>(W + h * 32 + quad * 4);
    const float4 w1 = *reinterpret_cast<const float4*>(W + h * 32 + 16 + quad * 4);
    half8 b;
    b[0] = (_Float16)(w0.x * scale); b[1] = (_Float16)(w0.y * scale);
    b[2] = (_Float16)(w0.z * scale); b[3] = (_Float16)(w0.w * scale);
    b[4] = (_Float16)(w1.x * scale); b[5] = (_Float16)(w1.y * scale);
    b[6] = (_Float16)(w1.z * scale); b[7] = (_Float16)(w1.w * scale);
    return b;
}

// ---- msg_m, two partial sets (k3 quads {0-3},{4-7}): 8 b128 reads + DPP
//      xor1+xor2; active lanes l&3==0 write set (l>>2)&1.  (R17-proven tree.)
__device__ __forceinline__ void phase_msgm(const unsigned* __restrict__ Xs,
                                           unsigned* __restrict__ MSGM, int t) {
    const int l = t & 63, w = t >> 6;
    const int k3 = l & 7;
    const int chunk = (l >> 3) & 3;
    const int mlow = ((l >> 5) & 1) | ((w & 15) << 1);
    const int chunkp = chunk ^ ((k3 >> 1) & 3);       // j-invariant (4j%4==0)
    const unsigned* p = Xs + mlow * 512 + k3 * 16 + chunkp * 4;
    half8 accA{}, accB{};
#pragma unroll
    for (int j = 0; j < 4; ++j) {                     // k = k3 + 8j
        accA += __builtin_bit_cast(half8, *(const uint4v*)(p + j * 128));
        accB += __builtin_bit_cast(half8, *(const uint4v*)(p + 16384 + j * 128));
    }
    uint4v sA = __builtin_bit_cast(uint4v, accA);
    uint4v sB = __builtin_bit_cast(uint4v, accB);
    sA = dpp_hadd<0xB1>(sA); sA = dpp_hadd<0x4E>(sA);
    sB = dpp_hadd<0xB1>(sB); sB = dpp_hadd<0x4E>(sB);
    if ((l & 3) == 0) {
        const int set = (l >> 2) & 1;                 // k3 quad {0-3} vs {4-7}
        *(uint4v*)(MSGM + msgm_off(mlow + set * 64, chunk)) = sA;       // m
        *(uint4v*)(MSGM + msgm_off(mlow + 32 + set * 64, chunk)) = sB;  // m+32
    }
}

// ---- layer-2-only msg_k read path: 8-node column sums + row_ror:8 combine
//      (i^8, symmetric -> direction-proof), writes quarter-sets 0-3 of MSGK.
__device__ __forceinline__ void phase_msgk2(const unsigned* __restrict__ Xs,
                                            unsigned* __restrict__ MSGK, int t) {
    const int l = t & 63, w = t >> 6;
    const int k3 = l & 7;
    const int k = ((w & 3) << 3) | k3;
    const int chunk = w >> 2;
    const int mo = l >> 3;
    const int chunkp = chunk ^ ((k3 >> 1) & 3);
    const unsigned* p = Xs + mo * 4096 + k * 16 + chunkp * 4;
    half8 acc{};
#pragma unroll
    for (int j = 0; j < 8; ++j)                       // m = mo*8 + j
        acc += __builtin_bit_cast(half8, *(const uint4v*)(p + j * 512));
    uint4v s = __builtin_bit_cast(uint4v, acc);
    s = dpp_hadd<0x128>(s);                           // combine mo bit0 (i^8)
    if ((l & 8) == 0) {
        const int qi = l >> 4;                        // m-quarter -> set
        *(uint4v*)(MSGK + msgk_off(qi, k, chunk)) = s;
    }
}

// ---- phase B: A-part 2 accumulating MFMAs (msg_m sets); B-part NSETS
//      accumulating MFMAs over MSGK partial sets.
template <int NSETS>
__device__ __forceinline__ void phase_small(const float* __restrict__ Wmg,
                                            const float* __restrict__ Wkg,
                                            const unsigned* __restrict__ MSGM,
                                            const unsigned* __restrict__ MSGK,
                                            unsigned* __restrict__ ABu, int t) {
    const int w = t >> 6, lane = t & 63;
    if (w < 12) {
        const int isb = (w >= 8);
        const int ww = isb ? (w - 8) : w;
        const int nt = ww >> 1, ht = ww & 1;
        const int quad = lane >> 4, col = lane & 15;
        const half8 afrag = load_wfrag(isb ? Wkg : Wmg, ht * 16 + col, quad, LAYER_SCALE);
        f32x4 c = {0.f, 0.f, 0.f, 0.f};
        if (isb) {
            const int kk = nt * 16 + col;
            const unsigned* bp = MSGK + msgk_off(0, kk, quad);
#pragma unroll
            for (int s = 0; s < NSETS; ++s) {
                const half8 bf = __builtin_bit_cast(half8, *(const uint4v*)(bp + s * 512));
                c = __builtin_amdgcn_mfma_f32_16x16x32_f16(afrag, bf, c, 0, 0, 0);
            }
        } else {
            const int r0 = nt * 16 + col;
#pragma unroll
            for (int s = 0; s < 2; ++s) {
                const half8 bf = __builtin_bit_cast(half8,
                    *(const uint4v*)(MSGM + msgm_off(r0 + s * 64, quad)));
                c = __builtin_amdgcn_mfma_f32_16x16x32_f16(afrag, bf, c, 0, 0, 0);
            }
        }
        uint2 st;
        st.x = pkz(c[0], c[1]);
        st.y = pkz(c[2], c[3]);
        const int abrow = (isb ? 64 : 0) + nt * 16 + col;
        *reinterpret_cast<uint2*>(ABu + abrow * 20 + quad * 4 + ht * 2) = st;
    }
}

// ---- phase C: D = Ws_tile x X_group^T in-place; ALSO accumulates next
//      layer's msg_k partial in registers (thread's 8 nodes share k) and
//      writes it as one b128 to MSGK[set = w>>1].
__device__ __forceinline__ void phase_main(const float* __restrict__ Wsg,
                                           unsigned* __restrict__ Xs,
                                           const unsigned* __restrict__ ABu,
                                           unsigned* __restrict__ MSGK, int t) {
    const int w = t >> 6, lane = t & 63;
    const int quad = lane >> 4, col = lane & 15;
    const half8 a0 = load_wfrag(Wsg, col, quad, LAYER_SCALE);        // h = col
    const half8 a1 = load_wfrag(Wsg, 16 + col, quad, LAYER_SCALE);   // h = col+16
    const uint4v* AB4 = reinterpret_cast<const uint4v*>(ABu);        // stride 5 uint4
    unsigned* xp = Xs + col * 16 + ((quad ^ ((col >> 1) & 3)) << 2); // swizzled chunk
    uint4v msgp = {0u, 0u, 0u, 0u};
#pragma unroll 4
    for (int i = 0; i < 8; ++i) {
        const int T = w + i * 16;          // node group T*16..T*16+15
        const int m = T >> 1;
        const int k0 = (T & 1) << 4;
        unsigned* xc = xp + T * 256;
        const half8 b = __builtin_bit_cast(half8, *(const uint4v*)xc);
        const int krow = 64 + k0 + col;
        const uint4v Am = AB4[m * 5 + quad];       // broadcast (wave-uniform row)
        const uint4v Bk = AB4[krow * 5 + quad];
        const float2 p00 = upk(hadd2u(Am.x, Bk.x));
        const float2 p01 = upk(hadd2u(Am.y, Bk.y));
        const float2 p10 = upk(hadd2u(Am.z, Bk.z));
        const float2 p11 = upk(hadd2u(Am.w, Bk.w));
        f32x4 c0 = {p00.x, p00.y, p01.x, p01.y};
        f32x4 c1 = {p10.x, p10.y, p11.x, p11.y};
        c0 = __builtin_amdgcn_mfma_f32_16x16x32_f16(a0, b, c0, 0, 0, 0);
        c1 = __builtin_amdgcn_mfma_f32_16x16x32_f16(a1, b, c1, 0, 0, 0);
        uint4v st;
        st.x = hmax0u(pkz(c0[0], c0[1]));
        st.y = hmax0u(pkz(c0[2], c0[3]));
        st.z = hmax0u(pkz(c1[0], c1[1]));
        st.w = hmax0u(pkz(c1[2], c1[3]));
        *(uint4v*)xc = st;
        msgp.x = hadd2u(msgp.x, st.x);
        msgp.y = hadd2u(msgp.y, st.y);
        msgp.z = hadd2u(msgp.z, st.z);
        msgp.w = hadd2u(msgp.w, st.w);
    }
    const int set = w >> 1;                          // 8 sets over 16 waves
    const int kk = ((w & 1) << 4) | col;             // thread's (shared) k
    *(uint4v*)(MSGK + msgk_off(set, kk, quad)) = msgp;
}

__global__ void __launch_bounds__(NTHREADS) gnn_fused(
    const float* __restrict__ xg,
    const float* __restrict__ w1s, const float* __restrict__ w1m, const float* __restrict__ w1k,
    const float* __restrict__ w2s, const float* __restrict__ w2m, const float* __restrict__ w2k,
    const float* __restrict__ w3s, const float* __restrict__ w3m, const float* __restrict__ w3k,
    const float* __restrict__ w4s, const float* __restrict__ w4m, const float* __restrict__ w4k,
    const float* __restrict__ w5s, const float* __restrict__ w5m, const float* __restrict__ w5k,
    float* __restrict__ out)
{
    __shared__ __align__(16) unsigned Xs[2048 * 16];   // 128 KiB, swizzled rows
    __shared__ __align__(16) unsigned MSGK[8 * 512];   // 16 KiB, 8 partial sets
    __shared__ __align__(16) unsigned MSGM[128 * 16];  // 8 KiB, msg_m 2 sets
    __shared__ __align__(16) unsigned ABu[96 * 20];    // 7.5 KiB
    __shared__ float red[17];

    const int t = threadIdx.x;
    const int b = blockIdx.x;
    const int k = t & 31;
    const int m1 = t >> 5;
    const int m2 = m1 + 32;
    const int lane = t & 63;
    const int wave = t >> 6;
    const int sw1 = (t >> 1) & 3;      // chunk swizzle for nodes t and t+1024

    float2 a1 = *reinterpret_cast<const float2*>(xg + (size_t)b * 4096 + 2 * t);
    float2 a2 = *reinterpret_cast<const float2*>(xg + (size_t)b * 4096 + 2048 + 2 * t);
    a1.x *= INPUT_SCALE; a1.y *= INPUT_SCALE;
    a2.x *= INPUT_SCALE; a2.y *= INPUT_SCALE;

    _Float16* ABf = reinterpret_cast<_Float16*>(ABu);
    float* MSGMf = reinterpret_cast<float*>(MSGM);

    // ================= layer 1 (d_in=2, scalar path) =================
    if (t < 64) MSGMf[t] = 0.f;
    __syncthreads();
    {
        float s0 = a1.x + a2.x, s1 = a1.y + a2.y;
        s0 += __shfl_xor(s0, 32);
        s1 += __shfl_xor(s1, 32);
        if (lane < 32) {
            atomicAdd(&MSGMf[2 * k], s0);
            atomicAdd(&MSGMf[2 * k + 1], s1);
        }
        float f0 = a1.x, f1 = a1.y, g0 = a2.x, g1 = a2.y;
#pragma unroll
        for (int mask = 1; mask <= 16; mask <<= 1) {
            f0 += __shfl_xor(f0, mask); f1 += __shfl_xor(f1, mask);
            g0 += __shfl_xor(g0, mask); g1 += __shfl_xor(g1, mask);
        }
        const float2 wm = *reinterpret_cast<const float2*>(w1m + 2 * k);
        ABf[m1 * 40 + AB_OFF(k)] = (_Float16)(wm.x * f0 + wm.y * f1);
        ABf[m2 * 40 + AB_OFF(k)] = (_Float16)(wm.x * g0 + wm.y * g1);
    }
    __syncthreads();
    {
        const int kk = t >> 5, hh = t & 31;
        const float2 wk2 = *reinterpret_cast<const float2*>(w1k + 2 * hh);
        ABf[(64 + kk) * 40 + AB_OFF(hh)] =
            (_Float16)(wk2.x * MSGMf[2 * kk] + wk2.y * MSGMf[2 * kk + 1]);
    }
    __syncthreads();
#pragma unroll 1
    for (int hf = 0; hf < 2; ++hf) {
        const int n = hf ? (t + 1024) : t;
        const int m = hf ? m2 : m1;
        const float xa = hf ? a2.x : a1.x;
        const float xb = hf ? a2.y : a1.y;
#define DECL_ACC(h) float acc##h = (float)ABf[m * 40 + AB_OFF(h)] \
                                 + (float)ABf[(64 + k) * 40 + AB_OFF(h)] \
                                 + w1s[h * 2] * xa + w1s[h * 2 + 1] * xb;
        RPT32(DECL_ACC)
#undef DECL_ACC
        unsigned tmp[16];
#define ST(p, h0, h1) tmp[p] = pkz(fmaxf(acc##h0, 0.f) * LAYER_SCALE, \
                                   fmaxf(acc##h1, 0.f) * LAYER_SCALE);
        RPT16P(ST)
#undef ST
        unsigned* xd = Xs + n * 16;
        uint4v v0, v1, v2, v3;                       // chunk q = pairs {2q,2q+1,8+2q,8+2q+1}
        v0.x = tmp[0]; v0.y = tmp[1]; v0.z = tmp[8];  v0.w = tmp[9];
        v1.x = tmp[2]; v1.y = tmp[3]; v1.z = tmp[10]; v1.w = tmp[11];
        v2.x = tmp[4]; v2.y = tmp[5]; v2.z = tmp[12]; v2.w = tmp[13];
        v3.x = tmp[6]; v3.y = tmp[7]; v3.z = tmp[14]; v3.w = tmp[15];
        *(uint4v*)(xd + ((0 ^ sw1) << 2)) = v0;
        *(uint4v*)(xd + ((1 ^ sw1) << 2)) = v1;
        *(uint4v*)(xd + ((2 ^ sw1) << 2)) = v2;
        *(uint4v*)(xd + ((3 ^ sw1) << 2)) = v3;
    }
    __syncthreads();

    // ================= layers 2-4 (MFMA path) =================
    // layer 2: full msg (read-path msg_k -> sets 0-3, msg_m 2 sets)
    phase_msgk2(Xs, MSGK, t);
    phase_msgm(Xs, MSGM, t); __syncthreads();
    phase_small<4>(w2m, w2k, MSGM, MSGK, ABu, t); __syncthreads();
    phase_main(w2s, Xs, ABu, MSGK, t); __syncthreads();   // writes msg_k(X3) sets 0-7

    phase_msgm(Xs, MSGM, t); __syncthreads();
    phase_small<8>(w3m, w3k, MSGM, MSGK, ABu, t); __syncthreads();
    phase_main(w3s, Xs, ABu, MSGK, t); __syncthreads();   // writes msg_k(X4)

    phase_msgm(Xs, MSGM, t); __syncthreads();
    phase_small<8>(w4m, w4k, MSGM, MSGK, ABu, t); __syncthreads();
    phase_main(w4s, Xs, ABu, MSGK, t); __syncthreads();   // writes msg_k(X5)

    // ================= layer 5 (d_out=2, scalar) =================
    phase_msgm(Xs, MSGM, t); __syncthreads();
    if (t < 128) {                       // A5[m][h] = Wm5[h,:].msg_m[m] (2 sets)
        const int m = t & 63, h = t >> 6;
        const int rot = (m >> 3) & 3;    // bank rotation
        float acc = 0.f;
#pragma unroll
        for (int s0 = 0; s0 < 16; ++s0) {
            const int s = (s0 & 12) | ((s0 + rot) & 3);
            const int pp = PSLOT(s);
            const int idx = msgm_off(m, s >> 2) + (s & 3);
            const float2 uA = upk(MSGM[idx]);            // set 0
            const float2 uB = upk(MSGM[idx + 1024]);     // set 1 (+64 rows)
            acc += w5m[h * 32 + 2 * pp] * (uA.x + uB.x)
                 + w5m[h * 32 + 2 * pp + 1] * (uA.y + uB.y);
        }
        ABf[m * 40 + h] = (_Float16)acc;             // AB_OFF(h)=h for h<4
    } else if (t < 384) {                // B5[k][h] over 8 sets, 4-way split
        const int idx = t - 128;         // 0..255
        const int sp = idx & 3;          // set pair
        const int kk = (idx >> 2) & 31;
        const int h = idx >> 7;          // 0..1
        float acc = 0.f;
#pragma unroll
        for (int s0 = 0; s0 < 16; ++s0) {
            const int s = (s0 & 12) | ((s0 + sp) & 3);   // bank rotation
            const int pp = PSLOT(s);
            const int off = msgk_off(0, kk, s >> 2) + (s & 3);
            const float2 u0 = upk(MSGK[(2 * sp) * 512 + off]);
            const float2 u1 = upk(MSGK[(2 * sp + 1) * 512 + off]);
            acc += w5k[h * 32 + 2 * pp] * (u0.x + u1.x)
                 + w5k[h * 32 + 2 * pp + 1] * (u0.y + u1.y);
        }
        acc += __shfl_xor(acc, 1);
        acc += __shfl_xor(acc, 2);
        if (sp == 0) ABf[(64 + kk) * 40 + h] = (_Float16)acc;
    }
    __syncthreads();

    float za0 = (float)ABf[m1 * 40 + 0] + (float)ABf[(64 + k) * 40 + 0];
    float za1 = (float)ABf[m1 * 40 + 1] + (float)ABf[(64 + k) * 40 + 1];
    float zb0 = (float)ABf[m2 * 40 + 0] + (float)ABf[(64 + k) * 40 + 0];
    float zb1 = (float)ABf[m2 * 40 + 1] + (float)ABf[(64 + k) * 40 + 1];
    {
        const unsigned* xa0 = Xs + t * 16;
        const unsigned* xb0 = xa0 + 16384;           // node t+1024, same sw1
#pragma unroll
        for (int s = 0; s < 16; ++s) {
            const int idx = ((((s >> 2) ^ sw1) << 2)) | (s & 3);
            const int pp = PSLOT(s);
            const float2 u = upk(xa0[idx]);
            za0 += w5s[2 * pp] * u.x + w5s[2 * pp + 1] * u.y;
            za1 += w5s[32 + 2 * pp] * u.x + w5s[32 + 2 * pp + 1] * u.y;
            const float2 v = upk(xb0[idx]);
            zb0 += w5s[2 * pp] * v.x + w5s[2 * pp + 1] * v.y;
            zb1 += w5s[32 + 2 * pp] * v.x + w5s[32 + 2 * pp + 1] * v.y;
        }
    }

    // ---- pwr_norm (scale-invariant: all per-item multipliers cancel) ----
    float p2 = za0 * za0 + za1 * za1 + zb0 * zb0 + zb1 * zb1;
#pragma unroll
    for (int mask = 1; mask <= 32; mask <<= 1) p2 += __shfl_xor(p2, mask);
    if (lane == 0) red[wave] = p2;
    __syncthreads();
    if (t == 0) {
        float tot = 0.f;
#pragma unroll
        for (int i = 0; i < 16; ++i) tot += red[i];
        red[16] = rsqrtf(tot);
    }
    __syncthreads();
    const float alpha = red[16];

    float2 r1, r2;
    r1.x = alpha * za0; r1.y = alpha * za1;
    r2.x = alpha * zb0; r2.y = alpha * zb1;
    *reinterpret_cast<float2*>(out + (size_t)b * 4096 + 2 * t) = r1;
    *reinterpret_cast<float2*>(out + (size_t)b * 4096 + 2048 + 2 * t) = r2;
}

}  // namespace

extern "C" void kernel_launch(void* const* d_in, const int* in_sizes, int n_in,
                              void* d_out, int out_size, void* d_ws, size_t ws_size,
                              hipStream_t stream) {
    const float* xg  = (const float*)d_in[0];
    const float* w1s = (const float*)d_in[1];
    const float* w1m = (const float*)d_in[2];
    const float* w1k = (const float*)d_in[3];
    const float* w2s = (const float*)d_in[4];
    const float* w2m = (const float*)d_in[5];
    const float* w2k = (const float*)d_in[6];
    const float* w3s = (const float*)d_in[7];
    const float* w3m = (const float*)d_in[8];
    const float* w3k = (const float*)d_in[9];
    const float* w4s = (const float*)d_in[10];
    const float* w4m = (const float*)d_in[11];
    const float* w4k = (const float*)d_in[12];
    const float* w5s = (const float*)d_in[13];
    const float* w5m = (const float*)d_in[14];
    const float* w5k = (const float*)d_in[15];
    float* out = (float*)d_out;

    hipLaunchKernelGGL(gnn_fused, dim3(1024), dim3(NTHREADS), 0, stream,
                       xg, w1s, w1m, w1k, w2s, w2m, w2k, w3s, w3m, w3k,
                       w4s, w4m, w4k, w5s, w5m, w5k, out);
}

// Round 9
// 196.701 us; speedup vs baseline: 1.1286x; 1.0223x over previous
//
#include <hip/hip_runtime.h>
#include <hip/hip_fp16.h>

// Precoding GNN: 5 layers of z = Ws*x + Wm*(sum_k x) + Wk*(sum_m x), ReLU(1-4),
// then Frobenius power normalization per batch item.
// M=64 antennas, K=32 users, D=32 hidden, BS=1024. One 1024-thread block/item.
//
// R19/20 (120us, conflicts 4.65M): layers 2-4 path optimized (register msg_k,
//   octet-exact swizzles); marginal time now in L1/L5 scalar LDS paths:
//   L1 issued 128 scalar ds_read_u16/thread (k-row ~4-way conflicted),
//   L5 output loop 32 scalar dword reads/thread.
// R21: vectorize L1/L5.
//  * L1: AB row quad q uint4 == chunk-q content == Xs store chunk. So:
//    read k-row as 4 b128 (bank groups 5k mod 8, conflict-free), m-row as
//    4 b128 (broadcast), pk_add m+k per dword, unpack, add Ws.x f32 terms
//    (h per element compile-time: chunk q elem e -> h0 table), relu*scale,
//    pack, store chunk (q^sw1). 12 b128 replace 128 scalar reads/thread.
//    fp16 pre-add of m+k matches phase_main's C-init (<=1 ulp, L1 only).
//  * L5 output loop: 4 b128 per node (8 total) replace 32 dword reads;
//    octet groups (4t + c') cover all 8 bank groups.
// All else byte-identical to R20. Numerics: absmax expected ~2.4-4e-4.

namespace {

constexpr int NTHREADS = 1024;
constexpr float INPUT_SCALE = 0.0625f;      // 2^-4 exact
constexpr float LAYER_SCALE = 0.0078125f;   // 2^-7 exact, folded into W frags

typedef _Float16 half8 __attribute__((ext_vector_type(8)));
typedef _Float16 half2v __attribute__((ext_vector_type(2)));
typedef float    f32x4 __attribute__((ext_vector_type(4)));
typedef unsigned uint4v __attribute__((ext_vector_type(4)));

// AB buffer: 96 rows x 20 dwords. Quad q's uint4 = halves [4q..4q+3, 16+4q..+3].
#define AB_OFF(h) ((((h) >> 2) & 3) * 8 + (((h) >> 4) & 1) * 4 + ((h) & 3))
// Feature-pair stored in slot s of a row: P(s) = 2*(s>>2) + 8*((s>>1)&1) + (s&1)
#define PSLOT(s) (2 * ((s) >> 2) + 8 * (((s) >> 1) & 1) + ((s) & 1))

// MSGK: 8 partial sets, dense 16-dword rows, XOR-swizzled chunk position.
__device__ __forceinline__ int msgk_off(int set, int k, int chunk) {
    return set * 512 + k * 16 + ((chunk ^ ((k >> 1) & 3)) << 2);
}
// MSGM: 2 partial sets (k3 quads {0-3}/{4-7}) x 64 m, dense 16-dword rows.
__device__ __forceinline__ int msgm_off(int row, int chunk) {
    return row * 16 + ((chunk ^ ((row >> 1) & 3)) << 2);
}

__device__ __forceinline__ float2 upk(unsigned w) {
    __half2 h;
    *reinterpret_cast<unsigned*>(&h) = w;
    return __half22float2(h);
}
__device__ __forceinline__ unsigned pkz(float a, float b) {   // v_cvt_pkrtz_f16_f32
    auto h = __builtin_amdgcn_cvt_pkrtz(a, b);   // __fp16 ext_vector(2)
    return __builtin_bit_cast(unsigned, h);
}
__device__ __forceinline__ unsigned hadd2u(unsigned a, unsigned b) {  // v_pk_add_f16
    half2v x = __builtin_bit_cast(half2v, a);
    half2v y = __builtin_bit_cast(half2v, b);
    return __builtin_bit_cast(unsigned, x + y);
}
__device__ __forceinline__ unsigned hmax0u(unsigned a) {      // v_pk_max_f16 with 0
    unsigned r;
    asm("v_pk_max_f16 %0, %1, 0" : "=v"(r) : "v"(a));
    return r;
}
// Cross-lane packed-fp16 add via DPP (VALU pipe, no LDS traffic).
// ONLY XOR-symmetric controls: 0xB1 quad_perm xor1, 0x4E quad_perm xor2,
// 0x128 row_ror:8 ((i+8)&15 == i^8, direction-proof).
template <int CTRL>
__device__ __forceinline__ uint4v dpp_hadd(uint4v s) {
    uint4v r;
    r.x = hadd2u(s.x, (unsigned)__builtin_amdgcn_mov_dpp((int)s.x, CTRL, 0xF, 0xF, true));
    r.y = hadd2u(s.y, (unsigned)__builtin_amdgcn_mov_dpp((int)s.y, CTRL, 0xF, 0xF, true));
    r.z = hadd2u(s.z, (unsigned)__builtin_amdgcn_mov_dpp((int)s.z, CTRL, 0xF, 0xF, true));
    r.w = hadd2u(s.w, (unsigned)__builtin_amdgcn_mov_dpp((int)s.w, CTRL, 0xF, 0xF, true));
    return r;
}

// Weight frag, PERMUTED K-order matching the chunk layout: lane (h, quad) gets
// halves [W[h][4q..4q+3], W[h][16+4q..16+4q+3]] * scale (pow2 -> exact fp16).
__device__ __forceinline__ half8 load_wfrag(const float* __restrict__ W, int h, int quad,
                                            float scale) {
    const float4 w0 = *reinterpret_cast<const float4*>(W + h * 32 + quad * 4);
    const float4 w1 = *reinterpret_cast<const float4*>(W + h * 32 + 16 + quad * 4);
    half8 b;
    b[0] = (_Float16)(w0.x * scale); b[1] = (_Float16)(w0.y * scale);
    b[2] = (_Float16)(w0.z * scale); b[3] = (_Float16)(w0.w * scale);
    b[4] = (_Float16)(w1.x * scale); b[5] = (_Float16)(w1.y * scale);
    b[6] = (_Float16)(w1.z * scale); b[7] = (_Float16)(w1.w * scale);
    return b;
}

// L1 element op: mk = pk_add(m-row, k-row) dword (features h0, h0+1);
// add Ws.x terms, relu, scale, pack.
__device__ __forceinline__ unsigned l1_proc(unsigned mk, const float* __restrict__ w1s,
                                            int h0, float xa, float xb) {
    const float2 f = upk(mk);
    const float a0 = f.x + w1s[h0 * 2] * xa + w1s[h0 * 2 + 1] * xb;
    const float a1 = f.y + w1s[h0 * 2 + 2] * xa + w1s[h0 * 2 + 3] * xb;
    return pkz(fmaxf(a0, 0.f) * LAYER_SCALE, fmaxf(a1, 0.f) * LAYER_SCALE);
}

// ---- msg_m, two partial sets (k3 quads {0-3},{4-7}): 8 b128 reads + DPP
//      xor1+xor2; active lanes l&3==0 write set (l>>2)&1.  (R17-proven tree.)
__device__ __forceinline__ void phase_msgm(const unsigned* __restrict__ Xs,
                                           unsigned* __restrict__ MSGM, int t) {
    const int l = t & 63, w = t >> 6;
    const int k3 = l & 7;
    const int chunk = (l >> 3) & 3;
    const int mlow = ((l >> 5) & 1) | ((w & 15) << 1);
    const int chunkp = chunk ^ ((k3 >> 1) & 3);       // j-invariant (4j%4==0)
    const unsigned* p = Xs + mlow * 512 + k3 * 16 + chunkp * 4;
    half8 accA{}, accB{};
#pragma unroll
    for (int j = 0; j < 4; ++j) {                     // k = k3 + 8j
        accA += __builtin_bit_cast(half8, *(const uint4v*)(p + j * 128));
        accB += __builtin_bit_cast(half8, *(const uint4v*)(p + 16384 + j * 128));
    }
    uint4v sA = __builtin_bit_cast(uint4v, accA);
    uint4v sB = __builtin_bit_cast(uint4v, accB);
    sA = dpp_hadd<0xB1>(sA); sA = dpp_hadd<0x4E>(sA);
    sB = dpp_hadd<0xB1>(sB); sB = dpp_hadd<0x4E>(sB);
    if ((l & 3) == 0) {
        const int set = (l >> 2) & 1;                 // k3 quad {0-3} vs {4-7}
        *(uint4v*)(MSGM + msgm_off(mlow + set * 64, chunk)) = sA;       // m
        *(uint4v*)(MSGM + msgm_off(mlow + 32 + set * 64, chunk)) = sB;  // m+32
    }
}

// ---- layer-2-only msg_k read path: 8-node column sums + row_ror:8 combine
//      (i^8, symmetric -> direction-proof), writes quarter-sets 0-3 of MSGK.
__device__ __forceinline__ void phase_msgk2(const unsigned* __restrict__ Xs,
                                            unsigned* __restrict__ MSGK, int t) {
    const int l = t & 63, w = t >> 6;
    const int k3 = l & 7;
    const int k = ((w & 3) << 3) | k3;
    const int chunk = w >> 2;
    const int mo = l >> 3;
    const int chunkp = chunk ^ ((k3 >> 1) & 3);
    const unsigned* p = Xs + mo * 4096 + k * 16 + chunkp * 4;
    half8 acc{};
#pragma unroll
    for (int j = 0; j < 8; ++j)                       // m = mo*8 + j
        acc += __builtin_bit_cast(half8, *(const uint4v*)(p + j * 512));
    uint4v s = __builtin_bit_cast(uint4v, acc);
    s = dpp_hadd<0x128>(s);                           // combine mo bit0 (i^8)
    if ((l & 8) == 0) {
        const int qi = l >> 4;                        // m-quarter -> set
        *(uint4v*)(MSGK + msgk_off(qi, k, chunk)) = s;
    }
}

// ---- phase B: A-part 2 accumulating MFMAs (msg_m sets); B-part NSETS
//      accumulating MFMAs over MSGK partial sets.
template <int NSETS>
__device__ __forceinline__ void phase_small(const float* __restrict__ Wmg,
                                            const float* __restrict__ Wkg,
                                            const unsigned* __restrict__ MSGM,
                                            const unsigned* __restrict__ MSGK,
                                            unsigned* __restrict__ ABu, int t) {
    const int w = t >> 6, lane = t & 63;
    if (w < 12) {
        const int isb = (w >= 8);
        const int ww = isb ? (w - 8) : w;
        const int nt = ww >> 1, ht = ww & 1;
        const int quad = lane >> 4, col = lane & 15;
        const half8 afrag = load_wfrag(isb ? Wkg : Wmg, ht * 16 + col, quad, LAYER_SCALE);
        f32x4 c = {0.f, 0.f, 0.f, 0.f};
        if (isb) {
            const int kk = nt * 16 + col;
            const unsigned* bp = MSGK + msgk_off(0, kk, quad);
#pragma unroll
            for (int s = 0; s < NSETS; ++s) {
                const half8 bf = __builtin_bit_cast(half8, *(const uint4v*)(bp + s * 512));
                c = __builtin_amdgcn_mfma_f32_16x16x32_f16(afrag, bf, c, 0, 0, 0);
            }
        } else {
            const int r0 = nt * 16 + col;
#pragma unroll
            for (int s = 0; s < 2; ++s) {
                const half8 bf = __builtin_bit_cast(half8,
                    *(const uint4v*)(MSGM + msgm_off(r0 + s * 64, quad)));
                c = __builtin_amdgcn_mfma_f32_16x16x32_f16(afrag, bf, c, 0, 0, 0);
            }
        }
        uint2 st;
        st.x = pkz(c[0], c[1]);
        st.y = pkz(c[2], c[3]);
        const int abrow = (isb ? 64 : 0) + nt * 16 + col;
        *reinterpret_cast<uint2*>(ABu + abrow * 20 + quad * 4 + ht * 2) = st;
    }
}

// ---- phase C: D = Ws_tile x X_group^T in-place; ALSO accumulates next
//      layer's msg_k partial in registers (thread's 8 nodes share k) and
//      writes it as one b128 to MSGK[set = w>>1].
__device__ __forceinline__ void phase_main(const float* __restrict__ Wsg,
                                           unsigned* __restrict__ Xs,
                                           const unsigned* __restrict__ ABu,
                                           unsigned* __restrict__ MSGK, int t) {
    const int w = t >> 6, lane = t & 63;
    const int quad = lane >> 4, col = lane & 15;
    const half8 a0 = load_wfrag(Wsg, col, quad, LAYER_SCALE);        // h = col
    const half8 a1 = load_wfrag(Wsg, 16 + col, quad, LAYER_SCALE);   // h = col+16
    const uint4v* AB4 = reinterpret_cast<const uint4v*>(ABu);        // stride 5 uint4
    unsigned* xp = Xs + col * 16 + ((quad ^ ((col >> 1) & 3)) << 2); // swizzled chunk
    uint4v msgp = {0u, 0u, 0u, 0u};
#pragma unroll 4
    for (int i = 0; i < 8; ++i) {
        const int T = w + i * 16;          // node group T*16..T*16+15
        const int m = T >> 1;
        const int k0 = (T & 1) << 4;
        unsigned* xc = xp + T * 256;
        const half8 b = __builtin_bit_cast(half8, *(const uint4v*)xc);
        const int krow = 64 + k0 + col;
        const uint4v Am = AB4[m * 5 + quad];       // broadcast (wave-uniform row)
        const uint4v Bk = AB4[krow * 5 + quad];
        const float2 p00 = upk(hadd2u(Am.x, Bk.x));
        const float2 p01 = upk(hadd2u(Am.y, Bk.y));
        const float2 p10 = upk(hadd2u(Am.z, Bk.z));
        const float2 p11 = upk(hadd2u(Am.w, Bk.w));
        f32x4 c0 = {p00.x, p00.y, p01.x, p01.y};
        f32x4 c1 = {p10.x, p10.y, p11.x, p11.y};
        c0 = __builtin_amdgcn_mfma_f32_16x16x32_f16(a0, b, c0, 0, 0, 0);
        c1 = __builtin_amdgcn_mfma_f32_16x16x32_f16(a1, b, c1, 0, 0, 0);
        uint4v st;
        st.x = hmax0u(pkz(c0[0], c0[1]));
        st.y = hmax0u(pkz(c0[2], c0[3]));
        st.z = hmax0u(pkz(c1[0], c1[1]));
        st.w = hmax0u(pkz(c1[2], c1[3]));
        *(uint4v*)xc = st;
        msgp.x = hadd2u(msgp.x, st.x);
        msgp.y = hadd2u(msgp.y, st.y);
        msgp.z = hadd2u(msgp.z, st.z);
        msgp.w = hadd2u(msgp.w, st.w);
    }
    const int set = w >> 1;                          // 8 sets over 16 waves
    const int kk = ((w & 1) << 4) | col;             // thread's (shared) k
    *(uint4v*)(MSGK + msgk_off(set, kk, quad)) = msgp;
}

__global__ void __launch_bounds__(NTHREADS) gnn_fused(
    const float* __restrict__ xg,
    const float* __restrict__ w1s, const float* __restrict__ w1m, const float* __restrict__ w1k,
    const float* __restrict__ w2s, const float* __restrict__ w2m, const float* __restrict__ w2k,
    const float* __restrict__ w3s, const float* __restrict__ w3m, const float* __restrict__ w3k,
    const float* __restrict__ w4s, const float* __restrict__ w4m, const float* __restrict__ w4k,
    const float* __restrict__ w5s, const float* __restrict__ w5m, const float* __restrict__ w5k,
    float* __restrict__ out)
{
    __shared__ __align__(16) unsigned Xs[2048 * 16];   // 128 KiB, swizzled rows
    __shared__ __align__(16) unsigned MSGK[8 * 512];   // 16 KiB, 8 partial sets
    __shared__ __align__(16) unsigned MSGM[128 * 16];  // 8 KiB, msg_m 2 sets
    __shared__ __align__(16) unsigned ABu[96 * 20];    // 7.5 KiB
    __shared__ float red[17];

    const int t = threadIdx.x;
    const int b = blockIdx.x;
    const int k = t & 31;
    const int m1 = t >> 5;
    const int m2 = m1 + 32;
    const int lane = t & 63;
    const int wave = t >> 6;
    const int sw1 = (t >> 1) & 3;      // chunk swizzle for nodes t and t+1024

    float2 a1 = *reinterpret_cast<const float2*>(xg + (size_t)b * 4096 + 2 * t);
    float2 a2 = *reinterpret_cast<const float2*>(xg + (size_t)b * 4096 + 2048 + 2 * t);
    a1.x *= INPUT_SCALE; a1.y *= INPUT_SCALE;
    a2.x *= INPUT_SCALE; a2.y *= INPUT_SCALE;

    _Float16* ABf = reinterpret_cast<_Float16*>(ABu);
    float* MSGMf = reinterpret_cast<float*>(MSGM);

    // ================= layer 1 (d_in=2, scalar path) =================
    if (t < 64) MSGMf[t] = 0.f;
    __syncthreads();
    {
        float s0 = a1.x + a2.x, s1 = a1.y + a2.y;
        s0 += __shfl_xor(s0, 32);
        s1 += __shfl_xor(s1, 32);
        if (lane < 32) {
            atomicAdd(&MSGMf[2 * k], s0);
            atomicAdd(&MSGMf[2 * k + 1], s1);
        }
        float f0 = a1.x, f1 = a1.y, g0 = a2.x, g1 = a2.y;
#pragma unroll
        for (int mask = 1; mask <= 16; mask <<= 1) {
            f0 += __shfl_xor(f0, mask); f1 += __shfl_xor(f1, mask);
            g0 += __shfl_xor(g0, mask); g1 += __shfl_xor(g1, mask);
        }
        const float2 wm = *reinterpret_cast<const float2*>(w1m + 2 * k);
        ABf[m1 * 40 + AB_OFF(k)] = (_Float16)(wm.x * f0 + wm.y * f1);
        ABf[m2 * 40 + AB_OFF(k)] = (_Float16)(wm.x * g0 + wm.y * g1);
    }
    __syncthreads();
    {
        const int kk = t >> 5, hh = t & 31;
        const float2 wk2 = *reinterpret_cast<const float2*>(w1k + 2 * hh);
        ABf[(64 + kk) * 40 + AB_OFF(hh)] =
            (_Float16)(wk2.x * MSGMf[2 * kk] + wk2.y * MSGMf[2 * kk + 1]);
    }
    __syncthreads();
    {
        // Vectorized L1 main: k-row once (4 b128, banks 5k mod 8 distinct),
        // m-row per half (broadcast), chunk q out = chunk q in (h0 table).
        const uint4v* krow4 = reinterpret_cast<const uint4v*>(ABu + (64 + k) * 20);
        const uint4v Kq0 = krow4[0], Kq1 = krow4[1], Kq2 = krow4[2], Kq3 = krow4[3];
#pragma unroll 1
        for (int hf = 0; hf < 2; ++hf) {
            const int n = hf ? (t + 1024) : t;
            const int m = hf ? m2 : m1;
            const float xa = hf ? a2.x : a1.x;
            const float xb = hf ? a2.y : a1.y;
            const uint4v* mrow4 = reinterpret_cast<const uint4v*>(ABu + m * 20);
            unsigned* xd = Xs + n * 16;
#define L1Q(q, Kq, H0, H1, H2, H3) { \
            const uint4v Mq = mrow4[q]; \
            uint4v R; \
            R.x = l1_proc(hadd2u(Mq.x, Kq.x), w1s, H0, xa, xb); \
            R.y = l1_proc(hadd2u(Mq.y, Kq.y), w1s, H1, xa, xb); \
            R.z = l1_proc(hadd2u(Mq.z, Kq.z), w1s, H2, xa, xb); \
            R.w = l1_proc(hadd2u(Mq.w, Kq.w), w1s, H3, xa, xb); \
            *(uint4v*)(xd + (((q) ^ sw1) << 2)) = R; }
            L1Q(0, Kq0, 0, 2, 16, 18)
            L1Q(1, Kq1, 4, 6, 20, 22)
            L1Q(2, Kq2, 8, 10, 24, 26)
            L1Q(3, Kq3, 12, 14, 28, 30)
#undef L1Q
        }
    }
    __syncthreads();

    // ================= layers 2-4 (MFMA path) =================
    // layer 2: full msg (read-path msg_k -> sets 0-3, msg_m 2 sets)
    phase_msgk2(Xs, MSGK, t);
    phase_msgm(Xs, MSGM, t); __syncthreads();
    phase_small<4>(w2m, w2k, MSGM, MSGK, ABu, t); __syncthreads();
    phase_main(w2s, Xs, ABu, MSGK, t); __syncthreads();   // writes msg_k(X3) sets 0-7

    phase_msgm(Xs, MSGM, t); __syncthreads();
    phase_small<8>(w3m, w3k, MSGM, MSGK, ABu, t); __syncthreads();
    phase_main(w3s, Xs, ABu, MSGK, t); __syncthreads();   // writes msg_k(X4)

    phase_msgm(Xs, MSGM, t); __syncthreads();
    phase_small<8>(w4m, w4k, MSGM, MSGK, ABu, t); __syncthreads();
    phase_main(w4s, Xs, ABu, MSGK, t); __syncthreads();   // writes msg_k(X5)

    // ================= layer 5 (d_out=2, scalar) =================
    phase_msgm(Xs, MSGM, t); __syncthreads();
    if (t < 128) {                       // A5[m][h] = Wm5[h,:].msg_m[m] (2 sets)
        const int m = t & 63, h = t >> 6;
        const int rot = (m >> 3) & 3;    // bank rotation
        float acc = 0.f;
#pragma unroll
        for (int s0 = 0; s0 < 16; ++s0) {
            const int s = (s0 & 12) | ((s0 + rot) & 3);
            const int pp = PSLOT(s);
            const int idx = msgm_off(m, s >> 2) + (s & 3);
            const float2 uA = upk(MSGM[idx]);            // set 0
            const float2 uB = upk(MSGM[idx + 1024]);     // set 1 (+64 rows)
            acc += w5m[h * 32 + 2 * pp] * (uA.x + uB.x)
                 + w5m[h * 32 + 2 * pp + 1] * (uA.y + uB.y);
        }
        ABf[m * 40 + h] = (_Float16)acc;             // AB_OFF(h)=h for h<4
    } else if (t < 384) {                // B5[k][h] over 8 sets, 4-way split
        const int idx = t - 128;         // 0..255
        const int sp = idx & 3;          // set pair
        const int kk = (idx >> 2) & 31;
        const int h = idx >> 7;          // 0..1
        float acc = 0.f;
#pragma unroll
        for (int s0 = 0; s0 < 16; ++s0) {
            const int s = (s0 & 12) | ((s0 + sp) & 3);   // bank rotation
            const int pp = PSLOT(s);
            const int off = msgk_off(0, kk, s >> 2) + (s & 3);
            const float2 u0 = upk(MSGK[(2 * sp) * 512 + off]);
            const float2 u1 = upk(MSGK[(2 * sp + 1) * 512 + off]);
            acc += w5k[h * 32 + 2 * pp] * (u0.x + u1.x)
                 + w5k[h * 32 + 2 * pp + 1] * (u0.y + u1.y);
        }
        acc += __shfl_xor(acc, 1);
        acc += __shfl_xor(acc, 2);
        if (sp == 0) ABf[(64 + kk) * 40 + h] = (_Float16)acc;
    }
    __syncthreads();

    float za0 = (float)ABf[m1 * 40 + 0] + (float)ABf[(64 + k) * 40 + 0];
    float za1 = (float)ABf[m1 * 40 + 1] + (float)ABf[(64 + k) * 40 + 1];
    float zb0 = (float)ABf[m2 * 40 + 0] + (float)ABf[(64 + k) * 40 + 0];
    float zb1 = (float)ABf[m2 * 40 + 1] + (float)ABf[(64 + k) * 40 + 1];
    {
        const unsigned* xa0 = Xs + t * 16;
        const unsigned* xb0 = xa0 + 16384;           // node t+1024, same sw1
#define L5E(uu, vv, s) { const int pp = PSLOT(s); \
        const float2 u = upk(uu); \
        za0 += w5s[2 * pp] * u.x + w5s[2 * pp + 1] * u.y; \
        za1 += w5s[32 + 2 * pp] * u.x + w5s[32 + 2 * pp + 1] * u.y; \
        const float2 v = upk(vv); \
        zb0 += w5s[2 * pp] * v.x + w5s[2 * pp + 1] * v.y; \
        zb1 += w5s[32 + 2 * pp] * v.x + w5s[32 + 2 * pp + 1] * v.y; }
#define L5C(c, S0) { \
        const uint4v U = *(const uint4v*)(xa0 + (((c) ^ sw1) << 2)); \
        const uint4v V = *(const uint4v*)(xb0 + (((c) ^ sw1) << 2)); \
        L5E(U.x, V.x, S0)     L5E(U.y, V.y, (S0) + 1) \
        L5E(U.z, V.z, (S0) + 2) L5E(U.w, V.w, (S0) + 3) }
        L5C(0, 0) L5C(1, 4) L5C(2, 8) L5C(3, 12)
#undef L5C
#undef L5E
    }

    // ---- pwr_norm (scale-invariant: all per-item multipliers cancel) ----
    float p2 = za0 * za0 + za1 * za1 + zb0 * zb0 + zb1 * zb1;
#pragma unroll
    for (int mask = 1; mask <= 32; mask <<= 1) p2 += __shfl_xor(p2, mask);
    if (lane == 0) red[wave] = p2;
    __syncthreads();
    if (t == 0) {
        float tot = 0.f;
#pragma unroll
        for (int i = 0; i < 16; ++i) tot += red[i];
        red[16] = rsqrtf(tot);
    }
    __syncthreads();
    const float alpha = red[16];

    float2 r1, r2;
    r1.x = alpha * za0; r1.y = alpha * za1;
    r2.x = alpha * zb0; r2.y = alpha * zb1;
    *reinterpret_cast<float2*>(out + (size_t)b * 4096 + 2 * t) = r1;
    *reinterpret_cast<float2*>(out + (size_t)b * 4096 + 2048 + 2 * t) = r2;
}

}  // namespace

extern "C" void kernel_launch(void* const* d_in, const int* in_sizes, int n_in,
                              void* d_out, int out_size, void* d_ws, size_t ws_size,
                              hipStream_t stream) {
    const float* xg  = (const float*)d_in[0];
    const float* w1s = (const float*)d_in[1];
    const float* w1m = (const float*)d_in[2];
    const float* w1k = (const float*)d_in[3];
    const float* w2s = (const float*)d_in[4];
    const float* w2m = (const float*)d_in[5];
    const float* w2k = (const float*)d_in[6];
    const float* w3s = (const float*)d_in[7];
    const float* w3m = (const float*)d_in[8];
    const float* w3k = (const float*)d_in[9];
    const float* w4s = (const float*)d_in[10];
    const float* w4m = (const float*)d_in[11];
    const float* w4k = (const float*)d_in[12];
    const float* w5s = (const float*)d_in[13];
    const float* w5m = (const float*)d_in[14];
    const float* w5k = (const float*)d_in[15];
    float* out = (float*)d_out;

    hipLaunchKernelGGL(gnn_fused, dim3(1024), dim3(NTHREADS), 0, stream,
                       xg, w1s, w1m, w1k, w2s, w2m, w2k, w3s, w3m, w3k,
                       w4s, w4m, w4k, w5s, w5m, w5k, out);
}